// Round 1
// baseline (2075.595 us; speedup 1.0000x reference)
//
#include <hip/hip_runtime.h>
#include <hip/hip_bf16.h>

#define N_NODES 50000
#define N_EDGES 800000
#define DIM     128
#define DIM2    256
#define NLAYER  5
#define NGRAPH  512
#define TDIM    10
#define VMAX    119

// ---------------- atom encoder: h[n,:] = sum_t emb[t, x[n,t], :] ----------------
__global__ void atom_encoder(const int* __restrict__ x, const float* __restrict__ emb,
                             float* __restrict__ h) {
    int node = blockIdx.x * 4 + (threadIdx.x >> 6);
    int lane = threadIdx.x & 63;
    if (node >= N_NODES) return;
    float2 acc = {0.f, 0.f};
    const int* xr = x + node * 9;
    #pragma unroll
    for (int t = 0; t < 9; ++t) {
        int v = xr[t];
        const float2* row = (const float2*)(emb + ((size_t)t * VMAX + v) * DIM);
        float2 e = row[lane];
        acc.x += e.x; acc.y += e.y;
    }
    ((float2*)(h + (size_t)node * DIM))[lane] = acc;
}

// ---------------- CSR build ----------------
__global__ void count_deg(const int* __restrict__ dst, int* __restrict__ deg) {
    int e = blockIdx.x * blockDim.x + threadIdx.x;
    if (e < N_EDGES) atomicAdd(&deg[dst[e]], 1);
}

__global__ void scan_a(const int* __restrict__ deg, int* __restrict__ rp, int* __restrict__ bsum) {
    __shared__ int s[512];
    int i = blockIdx.x * 512 + threadIdx.x;
    int v = (i < N_NODES) ? deg[i] : 0;
    s[threadIdx.x] = v;
    __syncthreads();
    for (int off = 1; off < 512; off <<= 1) {
        int t = (threadIdx.x >= off) ? s[threadIdx.x - off] : 0;
        __syncthreads();
        s[threadIdx.x] += t;
        __syncthreads();
    }
    if (i < N_NODES) rp[i] = s[threadIdx.x] - v;   // exclusive
    if (threadIdx.x == 511) bsum[blockIdx.x] = s[511];
}

__global__ void scan_b(const int* __restrict__ bsum, int* __restrict__ boff) {
    __shared__ int s[128];
    const int NB = 98;
    int v = (threadIdx.x < NB) ? bsum[threadIdx.x] : 0;
    s[threadIdx.x] = v;
    __syncthreads();
    for (int off = 1; off < 128; off <<= 1) {
        int t = (threadIdx.x >= off) ? s[threadIdx.x - off] : 0;
        __syncthreads();
        s[threadIdx.x] += t;
        __syncthreads();
    }
    if (threadIdx.x < NB) boff[threadIdx.x] = s[threadIdx.x] - v;
}

__global__ void scan_c(int* __restrict__ rp, const int* __restrict__ boff) {
    int i = blockIdx.x * 512 + threadIdx.x;
    if (i < N_NODES) rp[i] += boff[blockIdx.x];
    if (blockIdx.x == 0 && threadIdx.x == 0) rp[N_NODES] = N_EDGES;
}

__global__ void fill_csr(const int* __restrict__ src, const int* __restrict__ dst,
                         const int* __restrict__ rp, int* __restrict__ cursor,
                         int* __restrict__ col) {
    int e = blockIdx.x * blockDim.x + threadIdx.x;
    if (e < N_EDGES) {
        int d = dst[e];
        int pos = atomicAdd(&cursor[d], 1);
        col[rp[d] + pos] = src[e];
    }
}

// ---------------- per-node aggregation: agg[n,:] = sum_{e in in(n)} relu(h[src,:]) --------
__global__ void gather_agg(const float* __restrict__ h, const int* __restrict__ rp,
                           const int* __restrict__ col, float* __restrict__ agg) {
    int node = blockIdx.x * 4 + (threadIdx.x >> 6);
    int lane = threadIdx.x & 63;
    if (node >= N_NODES) return;
    int e0 = rp[node], e1 = rp[node + 1];
    float2 acc = {0.f, 0.f};
    for (int e = e0; e < e1; ++e) {
        int s = col[e];
        float2 v = ((const float2*)(h + (size_t)s * DIM))[lane];
        acc.x += fmaxf(v.x, 0.f);
        acc.y += fmaxf(v.y, 0.f);
    }
    ((float2*)(agg + (size_t)node * DIM))[lane] = acc;
}

// ---------------- tiled f32 GEMM with fused prologue ----------------
// MODE 0: A[m,k] = (1+eps)*h[m,k] + agg[m,k]          (K=128, NC=256)
// MODE 1: A[m,k] = relu(z[m,k]*scale[k] + shift[k])   (K=256, NC=128)
template <int K, int NC, int MODE>
__global__ __launch_bounds__(256) void gemm_k(
    const float* __restrict__ A0, const float* __restrict__ A1,
    const float* __restrict__ B, const float* __restrict__ bias,
    const float* __restrict__ scale, const float* __restrict__ shift,
    const float* __restrict__ epsArr, int layer, float* __restrict__ Cout) {
    const int BM = 64, BN = 64, BK = 32;
    __shared__ float As[BK][BM + 4];
    __shared__ float Bs[BK][BN + 4];
    int m0 = blockIdx.x * BM;
    int n0 = blockIdx.y * BN;
    int tid = threadIdx.x;
    float epsval = (MODE == 0) ? (1.0f + epsArr[layer]) : 0.0f;
    float c[4][4] = {};
    for (int k0 = 0; k0 < K; k0 += BK) {
        for (int i = tid; i < BM * BK; i += 256) {
            int m = i / BK, k = i % BK;
            float v = 0.f;
            int gm = m0 + m;
            if (gm < N_NODES) {
                int gk = k0 + k;
                if (MODE == 0) {
                    v = epsval * A0[(size_t)gm * K + gk] + A1[(size_t)gm * K + gk];
                } else {
                    float zz = A0[(size_t)gm * K + gk];
                    v = fmaxf(zz * scale[gk] + shift[gk], 0.f);
                }
            }
            As[k][m] = v;
        }
        for (int i = tid; i < BK * BN; i += 256) {
            int k = i / BN, n = i % BN;
            Bs[k][n] = B[(size_t)(k0 + k) * NC + n0 + n];
        }
        __syncthreads();
        int tr = (tid >> 4) * 4, tc = (tid & 15) * 4;
        #pragma unroll
        for (int k = 0; k < BK; ++k) {
            float a[4], b[4];
            #pragma unroll
            for (int j = 0; j < 4; ++j) a[j] = As[k][tr + j];
            #pragma unroll
            for (int j = 0; j < 4; ++j) b[j] = Bs[k][tc + j];
            #pragma unroll
            for (int xx = 0; xx < 4; ++xx)
                #pragma unroll
                for (int yy = 0; yy < 4; ++yy) c[xx][yy] += a[xx] * b[yy];
        }
        __syncthreads();
    }
    int tr = (tid >> 4) * 4, tc = (tid & 15) * 4;
    #pragma unroll
    for (int xx = 0; xx < 4; ++xx) {
        int gm = m0 + tr + xx;
        if (gm >= N_NODES) break;
        #pragma unroll
        for (int yy = 0; yy < 4; ++yy) {
            int gn = n0 + tc + yy;
            Cout[(size_t)gm * NC + gn] = c[xx][yy] + bias[gn];
        }
    }
}

// ---------------- column stats (sum, sumsq) ----------------
template <int C>
__global__ void colstats(const float* __restrict__ Z, float* __restrict__ ssum,
                         float* __restrict__ ssq) {
    int c = threadIdx.x;
    int rows_per = (N_NODES + gridDim.x - 1) / gridDim.x;
    int r0 = blockIdx.x * rows_per;
    int r1 = min(r0 + rows_per, N_NODES);
    float s = 0.f, q = 0.f;
    for (int r = r0; r < r1; ++r) {
        float v = Z[(size_t)r * C + c];
        s += v;
        q += v * v;
    }
    atomicAdd(&ssum[c], s);
    atomicAdd(&ssq[c], q);
}

template <int C>
__global__ void bn_finalize(const float* __restrict__ ssum, const float* __restrict__ ssq,
                            const float* __restrict__ g, const float* __restrict__ b,
                            float* __restrict__ scale, float* __restrict__ shift) {
    int c = threadIdx.x;
    float mean = ssum[c] * (1.0f / N_NODES);
    float var = ssq[c] * (1.0f / N_NODES) - mean * mean;
    float sc = g[c] * rsqrtf(var + 1e-5f);
    scale[c] = sc;
    shift[c] = b[c] - mean * sc;
}

__global__ void apply_bn_relu(const float* __restrict__ src, const float* __restrict__ scale,
                              const float* __restrict__ shift, float* __restrict__ dsth) {
    int i = blockIdx.x * 256 + threadIdx.x;
    if (i >= N_NODES * DIM / 4) return;
    float4 v = ((const float4*)src)[i];
    int c = (i * 4) & (DIM - 1);
    v.x = fmaxf(v.x * scale[c + 0] + shift[c + 0], 0.f);
    v.y = fmaxf(v.y * scale[c + 1] + shift[c + 1], 0.f);
    v.z = fmaxf(v.z * scale[c + 2] + shift[c + 2], 0.f);
    v.w = fmaxf(v.w * scale[c + 3] + shift[c + 3], 0.f);
    ((float4*)dsth)[i] = v;
}

// ---------------- pooling ----------------
__global__ void count_graph(const int* __restrict__ batch, int* __restrict__ gcnt) {
    int n = blockIdx.x * 256 + threadIdx.x;
    if (n < N_NODES) atomicAdd(&gcnt[batch[n]], 1);
}

__global__ void scan_g(const int* __restrict__ gcnt, int* __restrict__ gptr) {
    __shared__ int s[512];
    int v = gcnt[threadIdx.x];
    s[threadIdx.x] = v;
    __syncthreads();
    for (int off = 1; off < 512; off <<= 1) {
        int t = (threadIdx.x >= off) ? s[threadIdx.x - off] : 0;
        __syncthreads();
        s[threadIdx.x] += t;
        __syncthreads();
    }
    gptr[threadIdx.x] = s[threadIdx.x] - v;
    if (threadIdx.x == 511) gptr[512] = s[511];
}

__global__ void pool(const float* __restrict__ h, const int* __restrict__ gptr,
                     float* __restrict__ hg) {
    int g = blockIdx.x;
    int lane = threadIdx.x;
    int n0 = gptr[g], n1 = gptr[g + 1];
    float2 acc = {0.f, 0.f};
    for (int n = n0; n < n1; ++n) {
        float2 v = ((const float2*)(h + (size_t)n * DIM))[lane];
        acc.x += v.x; acc.y += v.y;
    }
    float inv = 1.0f / fmaxf((float)(n1 - n0), 1.0f);
    float2 r; r.x = acc.x * inv; r.y = acc.y * inv;
    ((float2*)(hg + (size_t)g * DIM))[lane] = r;
}

__global__ void outk(const float* __restrict__ hg, const float* __restrict__ Wout,
                     const float* __restrict__ bout, float* __restrict__ out) {
    __shared__ float s[DIM];
    int g = blockIdx.x;
    for (int d = threadIdx.x; d < DIM; d += 64) s[d] = hg[(size_t)g * DIM + d];
    __syncthreads();
    int t = threadIdx.x;
    if (t < TDIM) {
        float acc = bout[t];
        for (int d = 0; d < DIM; ++d) acc += s[d] * Wout[d * TDIM + t];
        out[g * TDIM + t] = acc;
    }
}

extern "C" void kernel_launch(void* const* d_in, const int* in_sizes, int n_in,
                              void* d_out, int out_size, void* d_ws, size_t ws_size,
                              hipStream_t stream) {
    const int*   x     = (const int*)d_in[0];
    const int*   ei    = (const int*)d_in[1];
    const int*   batch = (const int*)d_in[2];
    const float* emb   = (const float*)d_in[3];
    const float* W1    = (const float*)d_in[4];
    const float* b1    = (const float*)d_in[5];
    const float* g1    = (const float*)d_in[6];
    const float* be1   = (const float*)d_in[7];
    const float* W2    = (const float*)d_in[8];
    const float* b2    = (const float*)d_in[9];
    const float* epsA  = (const float*)d_in[10];
    const float* bng   = (const float*)d_in[11];
    const float* bnb   = (const float*)d_in[12];
    const float* Wout  = (const float*)d_in[13];
    const float* bout  = (const float*)d_in[14];
    float* out = (float*)d_out;

    const int* srcIdx = ei;
    const int* dstIdx = ei + N_EDGES;

    char* base = (char*)d_ws;
    size_t off = 0;
    auto alloc = [&](size_t bytes) {
        char* p = base + off;
        off = (off + bytes + 255) & ~(size_t)255;
        return p;
    };
    float* h    = (float*)alloc((size_t)N_NODES * DIM * 4);
    float* agg  = (float*)alloc((size_t)N_NODES * DIM * 4);   // also reused as h2
    float* z    = (float*)alloc((size_t)N_NODES * DIM2 * 4);
    int*   rp   = (int*)alloc((N_NODES + 1) * 4);
    int*   tmpN = (int*)alloc(N_NODES * 4);                   // deg, then cursor
    int*   col  = (int*)alloc(N_EDGES * 4);
    int*   bsum = (int*)alloc(128 * 4);
    int*   boff = (int*)alloc(128 * 4);
    int*   gcnt = (int*)alloc(NGRAPH * 4);
    int*   gptr = (int*)alloc((NGRAPH + 1) * 4);
    float* ssum = (float*)alloc(DIM2 * 4);
    float* ssq  = (float*)alloc(DIM2 * 4);
    float* scl  = (float*)alloc(DIM2 * 4);
    float* sft  = (float*)alloc(DIM2 * 4);
    float* hg   = (float*)alloc((size_t)NGRAPH * DIM * 4);

    // atom encoder
    atom_encoder<<<(N_NODES + 3) / 4, 256, 0, stream>>>(x, emb, h);

    // CSR build (reused by all 5 layers)
    hipMemsetAsync(tmpN, 0, N_NODES * 4, stream);
    count_deg<<<(N_EDGES + 255) / 256, 256, 0, stream>>>(dstIdx, tmpN);
    scan_a<<<98, 512, 0, stream>>>(tmpN, rp, bsum);
    scan_b<<<1, 128, 0, stream>>>(bsum, boff);
    scan_c<<<98, 512, 0, stream>>>(rp, boff);
    hipMemsetAsync(tmpN, 0, N_NODES * 4, stream);
    fill_csr<<<(N_EDGES + 255) / 256, 256, 0, stream>>>(srcIdx, dstIdx, rp, tmpN, col);

    // graph pooling CSR
    hipMemsetAsync(gcnt, 0, NGRAPH * 4, stream);
    count_graph<<<(N_NODES + 255) / 256, 256, 0, stream>>>(batch, gcnt);
    scan_g<<<1, 512, 0, stream>>>(gcnt, gptr);

    for (int i = 0; i < NLAYER; ++i) {
        gather_agg<<<(N_NODES + 3) / 4, 256, 0, stream>>>(h, rp, col, agg);

        dim3 grid1(782, 4);
        gemm_k<128, 256, 0><<<grid1, 256, 0, stream>>>(
            h, agg, W1 + (size_t)i * 128 * 256, b1 + i * 256,
            nullptr, nullptr, epsA, i, z);

        hipMemsetAsync(ssum, 0, DIM2 * 4, stream);
        hipMemsetAsync(ssq, 0, DIM2 * 4, stream);
        colstats<256><<<200, 256, 0, stream>>>(z, ssum, ssq);
        bn_finalize<256><<<1, 256, 0, stream>>>(ssum, ssq, g1 + i * 256, be1 + i * 256, scl, sft);

        dim3 grid2(782, 2);
        float* h2out = (i < NLAYER - 1) ? agg : h;
        gemm_k<256, 128, 1><<<grid2, 256, 0, stream>>>(
            z, nullptr, W2 + (size_t)i * 256 * 128, b2 + i * 128,
            scl, sft, nullptr, i, h2out);

        if (i < NLAYER - 1) {
            hipMemsetAsync(ssum, 0, DIM * 4, stream);
            hipMemsetAsync(ssq, 0, DIM * 4, stream);
            colstats<128><<<200, 128, 0, stream>>>(agg, ssum, ssq);
            bn_finalize<128><<<1, 128, 0, stream>>>(ssum, ssq, bng + i * 128, bnb + i * 128, scl, sft);
            apply_bn_relu<<<(N_NODES * DIM / 4 + 255) / 256, 256, 0, stream>>>(agg, scl, sft, h);
        }
    }

    pool<<<NGRAPH, 64, 0, stream>>>(h, gptr, hg);
    outk<<<NGRAPH, 64, 0, stream>>>(hg, Wout, bout, out);
}

// Round 2
// 1576.855 us; speedup vs baseline: 1.3163x; 1.3163x over previous
//
#include <hip/hip_runtime.h>
#include <hip/hip_bf16.h>

#define N_NODES 50000
#define N_EDGES 800000
#define DIM     128
#define DIM2    256
#define NLAYER  5
#define NGRAPH  512
#define TDIM    10
#define VMAX    119

typedef _Float16 f16x8 __attribute__((ext_vector_type(8)));
typedef _Float16 f16x2 __attribute__((ext_vector_type(2)));
typedef float    f32x4 __attribute__((ext_vector_type(4)));

// ---------------- weight convert + transpose to f16 [n][k] ----------------
__global__ void convert_w(const float* __restrict__ W1, const float* __restrict__ W2,
                          _Float16* __restrict__ W1t, _Float16* __restrict__ W2t) {
    int idx = blockIdx.x * 256 + threadIdx.x;
    if (idx >= NLAYER * DIM * DIM2) return;
    int l = idx / (DIM * DIM2);
    int rem = idx % (DIM * DIM2);
    // W1: [l][k=128][n=256] -> W1t: [l][n=256][k=128]
    int k1 = rem / DIM2, n1 = rem % DIM2;
    W1t[(size_t)l * DIM * DIM2 + (size_t)n1 * DIM + k1] = (_Float16)W1[idx];
    // W2: [l][k=256][n=128] -> W2t: [l][n=128][k=256]
    int k2 = rem / DIM, n2 = rem % DIM;
    W2t[(size_t)l * DIM * DIM2 + (size_t)n2 * DIM2 + k2] = (_Float16)W2[idx];
}

// ---------------- atom encoder -> h_raw f16 (GEMM1 input), h_relu f16 (gather input) ----
__global__ void atom_encoder(const int* __restrict__ x, const float* __restrict__ emb,
                             _Float16* __restrict__ hraw, _Float16* __restrict__ hrelu) {
    int node = blockIdx.x * 4 + (threadIdx.x >> 6);
    int lane = threadIdx.x & 63;
    if (node >= N_NODES) return;
    float2 acc = {0.f, 0.f};
    const int* xr = x + node * 9;
    #pragma unroll
    for (int t = 0; t < 9; ++t) {
        int v = xr[t];
        const float2* row = (const float2*)(emb + ((size_t)t * VMAX + v) * DIM);
        float2 e = row[lane];
        acc.x += e.x; acc.y += e.y;
    }
    f16x2 o, orl;
    o[0] = (_Float16)acc.x; o[1] = (_Float16)acc.y;
    orl[0] = (_Float16)fmaxf(acc.x, 0.f); orl[1] = (_Float16)fmaxf(acc.y, 0.f);
    ((f16x2*)(hraw + (size_t)node * DIM))[lane] = o;
    ((f16x2*)(hrelu + (size_t)node * DIM))[lane] = orl;
}

// ---------------- CSR build ----------------
__global__ void count_deg(const int* __restrict__ dst, int* __restrict__ deg) {
    int e = blockIdx.x * blockDim.x + threadIdx.x;
    if (e < N_EDGES) atomicAdd(&deg[dst[e]], 1);
}

__global__ void scan_a(const int* __restrict__ deg, int* __restrict__ rp, int* __restrict__ bsum) {
    __shared__ int s[512];
    int i = blockIdx.x * 512 + threadIdx.x;
    int v = (i < N_NODES) ? deg[i] : 0;
    s[threadIdx.x] = v;
    __syncthreads();
    for (int off = 1; off < 512; off <<= 1) {
        int t = (threadIdx.x >= off) ? s[threadIdx.x - off] : 0;
        __syncthreads();
        s[threadIdx.x] += t;
        __syncthreads();
    }
    if (i < N_NODES) rp[i] = s[threadIdx.x] - v;   // exclusive
    if (threadIdx.x == 511) bsum[blockIdx.x] = s[511];
}

__global__ void scan_b(const int* __restrict__ bsum, int* __restrict__ boff) {
    __shared__ int s[128];
    const int NB = 98;
    int v = (threadIdx.x < NB) ? bsum[threadIdx.x] : 0;
    s[threadIdx.x] = v;
    __syncthreads();
    for (int off = 1; off < 128; off <<= 1) {
        int t = (threadIdx.x >= off) ? s[threadIdx.x - off] : 0;
        __syncthreads();
        s[threadIdx.x] += t;
        __syncthreads();
    }
    if (threadIdx.x < NB) boff[threadIdx.x] = s[threadIdx.x] - v;
}

__global__ void scan_c(int* __restrict__ rp, const int* __restrict__ boff) {
    int i = blockIdx.x * 512 + threadIdx.x;
    if (i < N_NODES) rp[i] += boff[blockIdx.x];
    if (blockIdx.x == 0 && threadIdx.x == 0) rp[N_NODES] = N_EDGES;
}

__global__ void fill_csr(const int* __restrict__ src, const int* __restrict__ dst,
                         const int* __restrict__ rp, int* __restrict__ cursor,
                         int* __restrict__ col) {
    int e = blockIdx.x * blockDim.x + threadIdx.x;
    if (e < N_EDGES) {
        int d = dst[e];
        int pos = atomicAdd(&cursor[d], 1);
        col[rp[d] + pos] = src[e];
    }
}

// ---------------- aggregation: agg[n,:] = sum_{e in in(n)} hrelu[src,:]  (f16 rows) ----
__global__ void gather_agg(const _Float16* __restrict__ hrelu, const int* __restrict__ rp,
                           const int* __restrict__ col, _Float16* __restrict__ agg) {
    int node = blockIdx.x * 4 + (threadIdx.x >> 6);
    int lane = threadIdx.x & 63;
    if (node >= N_NODES) return;
    int e0 = rp[node], e1 = rp[node + 1];
    float2 acc = {0.f, 0.f};
    int e = e0;
    for (; e + 1 < e1; e += 2) {
        int s0 = col[e], s1 = col[e + 1];
        f16x2 v0 = ((const f16x2*)(hrelu + (size_t)s0 * DIM))[lane];
        f16x2 v1 = ((const f16x2*)(hrelu + (size_t)s1 * DIM))[lane];
        acc.x += (float)v0[0] + (float)v1[0];
        acc.y += (float)v0[1] + (float)v1[1];
    }
    if (e < e1) {
        int s0 = col[e];
        f16x2 v0 = ((const f16x2*)(hrelu + (size_t)s0 * DIM))[lane];
        acc.x += (float)v0[0];
        acc.y += (float)v0[1];
    }
    f16x2 o;
    o[0] = (_Float16)acc.x; o[1] = (_Float16)acc.y;
    ((f16x2*)(agg + (size_t)node * DIM))[lane] = o;
}

// ---------------- MFMA GEMM (f16 in, f32 acc, f16 out) ----------------
// MODE 0: A[m][k] = (1+eps)*h16[m][k] + agg16[m][k]      (K=128, NC=256)
// MODE 1: A[m][k] = relu(z16[m][k]*scale[k] + shift[k])  (K=256, NC=128)
// Bt is f16 [NC][K]. Each wave: 16 rows x NC cols. Block = 4 waves = 64 rows.
template <int K, int NC, int MODE>
__global__ __launch_bounds__(256) void gemm_mfma(
    const _Float16* __restrict__ A0h, const _Float16* __restrict__ A1h,
    const _Float16* __restrict__ Bt, const float* __restrict__ bias,
    const float* __restrict__ scale, const float* __restrict__ shift,
    const float* __restrict__ epsArr, int layer, _Float16* __restrict__ Cout) {
    const int NT = NC / 16;   // col tiles per wave
    const int KI = K / 32;    // k-steps
    int wave = threadIdx.x >> 6;
    int lane = threadIdx.x & 63;
    int quad = lane >> 4;
    int l16  = lane & 15;
    int m0 = blockIdx.x * 64 + wave * 16;
    if (m0 >= N_NODES) return;          // 50000 % 16 == 0: waves fully valid or fully out
    f32x4 acc[NT];
    #pragma unroll
    for (int nt = 0; nt < NT; ++nt) acc[nt] = (f32x4){0.f, 0.f, 0.f, 0.f};
    _Float16 ev = (MODE == 0) ? (_Float16)(1.0f + epsArr[layer]) : (_Float16)0;
    int mrow = m0 + l16;
    #pragma unroll
    for (int kt = 0; kt < KI; ++kt) {
        int kb = kt * 32 + quad * 8;
        f16x8 afrag;
        if (MODE == 0) {
            f16x8 hv = *(const f16x8*)(A0h + (size_t)mrow * K + kb);
            f16x8 av = *(const f16x8*)(A1h + (size_t)mrow * K + kb);
            #pragma unroll
            for (int j = 0; j < 8; ++j) afrag[j] = ev * hv[j] + av[j];
        } else {
            f16x8 zv = *(const f16x8*)(A0h + (size_t)mrow * K + kb);
            #pragma unroll
            for (int j = 0; j < 8; ++j) {
                float f = (float)zv[j] * scale[kb + j] + shift[kb + j];
                afrag[j] = (_Float16)fmaxf(f, 0.f);
            }
        }
        #pragma unroll
        for (int nt = 0; nt < NT; ++nt) {
            f16x8 bfrag = *(const f16x8*)(Bt + (size_t)(nt * 16 + l16) * K + kb);
            acc[nt] = __builtin_amdgcn_mfma_f32_16x16x32_f16(afrag, bfrag, acc[nt], 0, 0, 0);
        }
    }
    // C/D layout: col = lane&15, row = quad*4 + reg
    #pragma unroll
    for (int nt = 0; nt < NT; ++nt) {
        int c = nt * 16 + l16;
        float bv = bias[c];
        #pragma unroll
        for (int r = 0; r < 4; ++r)
            Cout[(size_t)(m0 + quad * 4 + r) * NC + c] = (_Float16)(acc[nt][r] + bv);
    }
}

// ---------------- column stats over f16 matrix ----------------
template <int C>
__global__ void colstats16(const _Float16* __restrict__ Z, float* __restrict__ ssum,
                           float* __restrict__ ssq) {
    int c = threadIdx.x;
    int rows_per = (N_NODES + gridDim.x - 1) / gridDim.x;
    int r0 = blockIdx.x * rows_per;
    int r1 = min(r0 + rows_per, N_NODES);
    float s = 0.f, q = 0.f;
    for (int r = r0; r < r1; ++r) {
        float v = (float)Z[(size_t)r * C + c];
        s += v;
        q += v * v;
    }
    atomicAdd(&ssum[c], s);
    atomicAdd(&ssq[c], q);
}

template <int C>
__global__ void bn_finalize(const float* __restrict__ ssum, const float* __restrict__ ssq,
                            const float* __restrict__ g, const float* __restrict__ b,
                            float* __restrict__ scale, float* __restrict__ shift) {
    int c = threadIdx.x;
    float mean = ssum[c] * (1.0f / N_NODES);
    float var = ssq[c] * (1.0f / N_NODES) - mean * mean;
    float sc = g[c] * rsqrtf(var + 1e-5f);
    scale[c] = sc;
    shift[c] = b[c] - mean * sc;
}

// outer BN + relu: h2 f16 -> h f16 (relu'd; serves both GEMM1-A and gather next layer)
__global__ void apply_bn_relu16(const _Float16* __restrict__ src, const float* __restrict__ scale,
                                const float* __restrict__ shift, _Float16* __restrict__ dsth) {
    int i = blockIdx.x * 256 + threadIdx.x;
    if (i >= N_NODES * DIM / 2) return;
    f16x2 v = ((const f16x2*)src)[i];
    int c = (i * 2) & (DIM - 1);
    float a = (float)v[0] * scale[c] + shift[c];
    float b = (float)v[1] * scale[c + 1] + shift[c + 1];
    f16x2 o;
    o[0] = (_Float16)fmaxf(a, 0.f);
    o[1] = (_Float16)fmaxf(b, 0.f);
    ((f16x2*)dsth)[i] = o;
}

// ---------------- pooling ----------------
__global__ void count_graph(const int* __restrict__ batch, int* __restrict__ gcnt) {
    int n = blockIdx.x * 256 + threadIdx.x;
    if (n < N_NODES) atomicAdd(&gcnt[batch[n]], 1);
}

__global__ void scan_g(const int* __restrict__ gcnt, int* __restrict__ gptr) {
    __shared__ int s[512];
    int v = gcnt[threadIdx.x];
    s[threadIdx.x] = v;
    __syncthreads();
    for (int off = 1; off < 512; off <<= 1) {
        int t = (threadIdx.x >= off) ? s[threadIdx.x - off] : 0;
        __syncthreads();
        s[threadIdx.x] += t;
        __syncthreads();
    }
    gptr[threadIdx.x] = s[threadIdx.x] - v;
    if (threadIdx.x == 511) gptr[512] = s[511];
}

__global__ void pool16(const _Float16* __restrict__ h, const int* __restrict__ gptr,
                       float* __restrict__ hg) {
    int g = blockIdx.x;
    int lane = threadIdx.x;
    int n0 = gptr[g], n1 = gptr[g + 1];
    float2 acc = {0.f, 0.f};
    for (int n = n0; n < n1; ++n) {
        f16x2 v = ((const f16x2*)(h + (size_t)n * DIM))[lane];
        acc.x += (float)v[0]; acc.y += (float)v[1];
    }
    float inv = 1.0f / fmaxf((float)(n1 - n0), 1.0f);
    float2 r; r.x = acc.x * inv; r.y = acc.y * inv;
    ((float2*)(hg + (size_t)g * DIM))[lane] = r;
}

__global__ void outk(const float* __restrict__ hg, const float* __restrict__ Wout,
                     const float* __restrict__ bout, float* __restrict__ out) {
    __shared__ float s[DIM];
    int g = blockIdx.x;
    for (int d = threadIdx.x; d < DIM; d += 64) s[d] = hg[(size_t)g * DIM + d];
    __syncthreads();
    int t = threadIdx.x;
    if (t < TDIM) {
        float acc = bout[t];
        for (int d = 0; d < DIM; ++d) acc += s[d] * Wout[d * TDIM + t];
        out[g * TDIM + t] = acc;
    }
}

extern "C" void kernel_launch(void* const* d_in, const int* in_sizes, int n_in,
                              void* d_out, int out_size, void* d_ws, size_t ws_size,
                              hipStream_t stream) {
    const int*   x     = (const int*)d_in[0];
    const int*   ei    = (const int*)d_in[1];
    const int*   batch = (const int*)d_in[2];
    const float* emb   = (const float*)d_in[3];
    const float* W1    = (const float*)d_in[4];
    const float* b1    = (const float*)d_in[5];
    const float* g1    = (const float*)d_in[6];
    const float* be1   = (const float*)d_in[7];
    const float* W2    = (const float*)d_in[8];
    const float* b2    = (const float*)d_in[9];
    const float* epsA  = (const float*)d_in[10];
    const float* bng   = (const float*)d_in[11];
    const float* bnb   = (const float*)d_in[12];
    const float* Wout  = (const float*)d_in[13];
    const float* bout  = (const float*)d_in[14];
    float* out = (float*)d_out;

    const int* srcIdx = ei;
    const int* dstIdx = ei + N_EDGES;

    char* base = (char*)d_ws;
    size_t off = 0;
    auto alloc = [&](size_t bytes) {
        char* p = base + off;
        off = (off + bytes + 255) & ~(size_t)255;
        return p;
    };
    _Float16* hraw  = (_Float16*)alloc((size_t)N_NODES * DIM * 2);   // layer-0 GEMM1 A input
    _Float16* hrel  = (_Float16*)alloc((size_t)N_NODES * DIM * 2);   // gather input / h for layers>=1
    _Float16* agg   = (_Float16*)alloc((size_t)N_NODES * DIM * 2);
    _Float16* z16   = (_Float16*)alloc((size_t)N_NODES * DIM2 * 2);
    _Float16* h2    = (_Float16*)alloc((size_t)N_NODES * DIM * 2);   // GEMM2 out
    _Float16* W1t   = (_Float16*)alloc((size_t)NLAYER * DIM * DIM2 * 2);
    _Float16* W2t   = (_Float16*)alloc((size_t)NLAYER * DIM * DIM2 * 2);
    int*   rp   = (int*)alloc((N_NODES + 1) * 4);
    int*   tmpN = (int*)alloc(N_NODES * 4);                          // deg, then cursor
    int*   col  = (int*)alloc(N_EDGES * 4);
    int*   bsum = (int*)alloc(128 * 4);
    int*   boff = (int*)alloc(128 * 4);
    int*   gcnt = (int*)alloc(NGRAPH * 4);
    int*   gptr = (int*)alloc((NGRAPH + 1) * 4);
    float* ssum = (float*)alloc(DIM2 * 4);
    float* ssq  = (float*)alloc(DIM2 * 4);
    float* scl  = (float*)alloc(DIM2 * 4);
    float* sft  = (float*)alloc(DIM2 * 4);
    float* hg   = (float*)alloc((size_t)NGRAPH * DIM * 4);

    // weight convert/transpose (L2-resident for the whole run)
    convert_w<<<(NLAYER * DIM * DIM2 + 255) / 256, 256, 0, stream>>>(W1, W2, W1t, W2t);

    // atom encoder
    atom_encoder<<<N_NODES / 4, 256, 0, stream>>>(x, emb, hraw, hrel);

    // CSR build (reused by all 5 layers)
    hipMemsetAsync(tmpN, 0, N_NODES * 4, stream);
    count_deg<<<(N_EDGES + 255) / 256, 256, 0, stream>>>(dstIdx, tmpN);
    scan_a<<<98, 512, 0, stream>>>(tmpN, rp, bsum);
    scan_b<<<1, 128, 0, stream>>>(bsum, boff);
    scan_c<<<98, 512, 0, stream>>>(rp, boff);
    hipMemsetAsync(tmpN, 0, N_NODES * 4, stream);
    fill_csr<<<(N_EDGES + 255) / 256, 256, 0, stream>>>(srcIdx, dstIdx, rp, tmpN, col);

    // graph pooling CSR
    hipMemsetAsync(gcnt, 0, NGRAPH * 4, stream);
    count_graph<<<(N_NODES + 255) / 256, 256, 0, stream>>>(batch, gcnt);
    scan_g<<<1, 512, 0, stream>>>(gcnt, gptr);

    const int GEMM_GRID = (N_NODES + 63) / 64;  // 782

    for (int i = 0; i < NLAYER; ++i) {
        const _Float16* hA = (i == 0) ? hraw : hrel;   // GEMM1 A (pre-relu only at layer 0)

        gather_agg<<<N_NODES / 4, 256, 0, stream>>>(hrel, rp, col, agg);

        gemm_mfma<128, 256, 0><<<GEMM_GRID, 256, 0, stream>>>(
            hA, agg, W1t + (size_t)i * DIM * DIM2, b1 + i * 256,
            nullptr, nullptr, epsA, i, z16);

        hipMemsetAsync(ssum, 0, DIM2 * 4, stream);
        hipMemsetAsync(ssq, 0, DIM2 * 4, stream);
        colstats16<256><<<200, 256, 0, stream>>>(z16, ssum, ssq);
        bn_finalize<256><<<1, 256, 0, stream>>>(ssum, ssq, g1 + i * 256, be1 + i * 256, scl, sft);

        gemm_mfma<256, 128, 1><<<GEMM_GRID, 256, 0, stream>>>(
            z16, nullptr, W2t + (size_t)i * DIM * DIM2, b2 + i * 128,
            scl, sft, epsA, i, h2);

        if (i < NLAYER - 1) {
            hipMemsetAsync(ssum, 0, DIM * 4, stream);
            hipMemsetAsync(ssq, 0, DIM * 4, stream);
            colstats16<128><<<200, 128, 0, stream>>>(h2, ssum, ssq);
            bn_finalize<128><<<1, 128, 0, stream>>>(ssum, ssq, bng + i * 128, bnb + i * 128, scl, sft);
            apply_bn_relu16<<<N_NODES * DIM / 2 / 256, 256, 0, stream>>>(h2, scl, sft, hrel);
        }
    }

    pool16<<<NGRAPH, 64, 0, stream>>>(h2, gptr, hg);
    outk<<<NGRAPH, 64, 0, stream>>>(hg, Wout, bout, out);
}

// Round 3
// 1467.673 us; speedup vs baseline: 1.4142x; 1.0744x over previous
//
#include <hip/hip_runtime.h>
#include <hip/hip_bf16.h>

#define N_NODES 50000
#define N_EDGES 800000
#define DIM     128
#define DIM2    256
#define NLAYER  5
#define NGRAPH  512
#define TDIM    10
#define VMAX    119

typedef _Float16 f16x8 __attribute__((ext_vector_type(8)));
typedef _Float16 f16x2 __attribute__((ext_vector_type(2)));
typedef float    f32x4 __attribute__((ext_vector_type(4)));

// ---------------- weight convert + transpose to f16 [n][k] ----------------
__global__ void convert_w(const float* __restrict__ W1, const float* __restrict__ W2,
                          _Float16* __restrict__ W1t, _Float16* __restrict__ W2t) {
    int idx = blockIdx.x * 256 + threadIdx.x;
    if (idx >= NLAYER * DIM * DIM2) return;
    int l = idx / (DIM * DIM2);
    int rem = idx % (DIM * DIM2);
    int k1 = rem / DIM2, n1 = rem % DIM2;
    W1t[(size_t)l * DIM * DIM2 + (size_t)n1 * DIM + k1] = (_Float16)W1[idx];
    int k2 = rem / DIM, n2 = rem % DIM;
    W2t[(size_t)l * DIM * DIM2 + (size_t)n2 * DIM2 + k2] = (_Float16)W2[idx];
}

// ---------------- atom encoder -> hraw f16 (GEMM1 layer0 A), hrel f16 (layer0 gather) ---
__global__ void atom_encoder(const int* __restrict__ x, const float* __restrict__ emb,
                             _Float16* __restrict__ hraw, _Float16* __restrict__ hrelu) {
    int node = blockIdx.x * 4 + (threadIdx.x >> 6);
    int lane = threadIdx.x & 63;
    if (node >= N_NODES) return;
    float2 acc = {0.f, 0.f};
    const int* xr = x + node * 9;
    #pragma unroll
    for (int t = 0; t < 9; ++t) {
        int v = xr[t];
        const float2* row = (const float2*)(emb + ((size_t)t * VMAX + v) * DIM);
        float2 e = row[lane];
        acc.x += e.x; acc.y += e.y;
    }
    f16x2 o, orl;
    o[0] = (_Float16)acc.x; o[1] = (_Float16)acc.y;
    orl[0] = (_Float16)fmaxf(acc.x, 0.f); orl[1] = (_Float16)fmaxf(acc.y, 0.f);
    ((f16x2*)(hraw + (size_t)node * DIM))[lane] = o;
    ((f16x2*)(hrelu + (size_t)node * DIM))[lane] = orl;
}

// ---------------- CSR build ----------------
__global__ void count_deg(const int* __restrict__ dst, int* __restrict__ deg) {
    int e = blockIdx.x * blockDim.x + threadIdx.x;
    if (e < N_EDGES) atomicAdd(&deg[dst[e]], 1);
}

__global__ void scan_a(const int* __restrict__ deg, int* __restrict__ rp, int* __restrict__ bsum) {
    __shared__ int s[512];
    int i = blockIdx.x * 512 + threadIdx.x;
    int v = (i < N_NODES) ? deg[i] : 0;
    s[threadIdx.x] = v;
    __syncthreads();
    for (int off = 1; off < 512; off <<= 1) {
        int t = (threadIdx.x >= off) ? s[threadIdx.x - off] : 0;
        __syncthreads();
        s[threadIdx.x] += t;
        __syncthreads();
    }
    if (i < N_NODES) rp[i] = s[threadIdx.x] - v;   // exclusive
    if (threadIdx.x == 511) bsum[blockIdx.x] = s[511];
}

__global__ void scan_b(const int* __restrict__ bsum, int* __restrict__ boff) {
    __shared__ int s[128];
    const int NB = 98;
    int v = (threadIdx.x < NB) ? bsum[threadIdx.x] : 0;
    s[threadIdx.x] = v;
    __syncthreads();
    for (int off = 1; off < 128; off <<= 1) {
        int t = (threadIdx.x >= off) ? s[threadIdx.x - off] : 0;
        __syncthreads();
        s[threadIdx.x] += t;
        __syncthreads();
    }
    if (threadIdx.x < NB) boff[threadIdx.x] = s[threadIdx.x] - v;
}

__global__ void scan_c(int* __restrict__ rp, const int* __restrict__ boff) {
    int i = blockIdx.x * 512 + threadIdx.x;
    if (i < N_NODES) rp[i] += boff[blockIdx.x];
    if (blockIdx.x == 0 && threadIdx.x == 0) rp[N_NODES] = N_EDGES;
}

__global__ void fill_csr(const int* __restrict__ src, const int* __restrict__ dst,
                         const int* __restrict__ rp, int* __restrict__ cursor,
                         int* __restrict__ col) {
    int e = blockIdx.x * blockDim.x + threadIdx.x;
    if (e < N_EDGES) {
        int d = dst[e];
        int pos = atomicAdd(&cursor[d], 1);
        col[rp[d] + pos] = src[e];
    }
}

// -------- aggregation. APPLY_BN=0: rows already relu'd. APPLY_BN=1: relu(v*sc+sh) ------
template <int APPLY_BN>
__global__ void gather_agg(const _Float16* __restrict__ hsrc, const int* __restrict__ rp,
                           const int* __restrict__ col, const float* __restrict__ scale,
                           const float* __restrict__ shift, _Float16* __restrict__ agg) {
    int node = blockIdx.x * 4 + (threadIdx.x >> 6);
    int lane = threadIdx.x & 63;
    if (node >= N_NODES) return;
    float sc0 = 0.f, sc1 = 0.f, sh0 = 0.f, sh1 = 0.f;
    if (APPLY_BN) {
        sc0 = scale[lane * 2]; sc1 = scale[lane * 2 + 1];
        sh0 = shift[lane * 2]; sh1 = shift[lane * 2 + 1];
    }
    int e0 = rp[node], e1 = rp[node + 1];
    float2 acc = {0.f, 0.f};
    for (int e = e0; e < e1; ++e) {
        int s = col[e];
        f16x2 v = ((const f16x2*)(hsrc + (size_t)s * DIM))[lane];
        float a = (float)v[0], b = (float)v[1];
        if (APPLY_BN) {
            a = fmaxf(a * sc0 + sh0, 0.f);
            b = fmaxf(b * sc1 + sh1, 0.f);
        }
        acc.x += a; acc.y += b;
    }
    f16x2 o;
    o[0] = (_Float16)acc.x; o[1] = (_Float16)acc.y;
    ((f16x2*)(agg + (size_t)node * DIM))[lane] = o;
}

// ---------------- MFMA GEMM, B staged in LDS, 32 rows/wave, fused BN-stats epilogue ----
// MODE 0: A[m][k] = (1+eps) * f(A0[m][k]) + A1[m][k], f = BN-relu if APPLY_BN else id
// MODE 1: A[m][k] = relu(A0[m][k]*scale[k] + shift[k])
// Bt f16 [NC][K]. Block = 4 waves x 32 rows = 128 rows. Stats: osum/osq += col sums of C.
template <int K, int NC, int MODE, int APPLY_BN, int STATS>
__global__ __launch_bounds__(256) void gemm_mfma(
    const _Float16* __restrict__ A0h, const _Float16* __restrict__ A1h,
    const _Float16* __restrict__ Bt, const float* __restrict__ bias,
    const float* __restrict__ scale, const float* __restrict__ shift,
    const float* __restrict__ epsArr, int layer, _Float16* __restrict__ Cout,
    float* __restrict__ osum, float* __restrict__ osq) {
    const int NT = NC / 16;       // 16-col tiles per wave
    const int KI = K / 32;        // k-steps
    const int KP = K + 8;         // padded LDS stride (f16) -> 16B-aligned rows, spread banks
    __shared__ _Float16 Bs[NC * KP];
    int tid = threadIdx.x;
    int wave = tid >> 6, lane = tid & 63, quad = lane >> 4, l16 = lane & 15;

    // stage B into LDS (once per block)
    for (int i = tid; i < NC * K / 8; i += 256) {
        int n = (i * 8) / K, k = (i * 8) % K;
        *(f16x8*)(&Bs[n * KP + k]) = *(const f16x8*)(Bt + (size_t)n * K + k);
    }
    __syncthreads();

    int m0 = blockIdx.x * 128 + wave * 32;
    if (m0 >= N_NODES) return;     // no barriers after this point
    int mt1 = m0 + 16;
    bool t1v = (mt1 < N_NODES);    // 50000 % 16 == 0: tiles fully valid or fully invalid
    int mrow0 = m0 + l16;
    int mrow1 = t1v ? (mt1 + l16) : mrow0;

    f32x4 acc0[NT], acc1[NT];
    #pragma unroll
    for (int nt = 0; nt < NT; ++nt) { acc0[nt] = (f32x4){0,0,0,0}; acc1[nt] = (f32x4){0,0,0,0}; }
    float evf = (MODE == 0) ? (1.0f + epsArr[layer]) : 0.0f;

    #pragma unroll
    for (int kt = 0; kt < KI; ++kt) {
        int kb = kt * 32 + quad * 8;
        f32x4 sc0v, sc1v, sh0v, sh1v;
        if (MODE == 1 || APPLY_BN) {
            sc0v = *(const f32x4*)(scale + kb); sc1v = *(const f32x4*)(scale + kb + 4);
            sh0v = *(const f32x4*)(shift + kb); sh1v = *(const f32x4*)(shift + kb + 4);
        }
        f16x8 afrag0, afrag1;
        if (MODE == 0) {
            f16x8 h0 = *(const f16x8*)(A0h + (size_t)mrow0 * K + kb);
            f16x8 h1 = *(const f16x8*)(A0h + (size_t)mrow1 * K + kb);
            f16x8 a0 = *(const f16x8*)(A1h + (size_t)mrow0 * K + kb);
            f16x8 a1 = *(const f16x8*)(A1h + (size_t)mrow1 * K + kb);
            #pragma unroll
            for (int j = 0; j < 8; ++j) {
                float f0 = (float)h0[j], f1 = (float)h1[j];
                if (APPLY_BN) {
                    float sc = (j < 4) ? sc0v[j & 3] : sc1v[j & 3];
                    float sh = (j < 4) ? sh0v[j & 3] : sh1v[j & 3];
                    f0 = fmaxf(f0 * sc + sh, 0.f);
                    f1 = fmaxf(f1 * sc + sh, 0.f);
                }
                afrag0[j] = (_Float16)(evf * f0 + (float)a0[j]);
                afrag1[j] = (_Float16)(evf * f1 + (float)a1[j]);
            }
        } else {
            f16x8 z0 = *(const f16x8*)(A0h + (size_t)mrow0 * K + kb);
            f16x8 z1 = *(const f16x8*)(A0h + (size_t)mrow1 * K + kb);
            #pragma unroll
            for (int j = 0; j < 8; ++j) {
                float sc = (j < 4) ? sc0v[j & 3] : sc1v[j & 3];
                float sh = (j < 4) ? sh0v[j & 3] : sh1v[j & 3];
                afrag0[j] = (_Float16)fmaxf((float)z0[j] * sc + sh, 0.f);
                afrag1[j] = (_Float16)fmaxf((float)z1[j] * sc + sh, 0.f);
            }
        }
        #pragma unroll
        for (int nt = 0; nt < NT; ++nt) {
            f16x8 bfrag = *(const f16x8*)(&Bs[(nt * 16 + l16) * KP + kb]);
            acc0[nt] = __builtin_amdgcn_mfma_f32_16x16x32_f16(afrag0, bfrag, acc0[nt], 0, 0, 0);
            acc1[nt] = __builtin_amdgcn_mfma_f32_16x16x32_f16(afrag1, bfrag, acc1[nt], 0, 0, 0);
        }
    }

    // epilogue: C layout col = l16, row = quad*4 + r
    #pragma unroll
    for (int nt = 0; nt < NT; ++nt) {
        int c = nt * 16 + l16;
        float bv = bias[c];
        float v0[4], v1[4];
        #pragma unroll
        for (int r = 0; r < 4; ++r) { v0[r] = acc0[nt][r] + bv; v1[r] = acc1[nt][r] + bv; }
        #pragma unroll
        for (int r = 0; r < 4; ++r)
            Cout[(size_t)(m0 + quad * 4 + r) * NC + c] = (_Float16)v0[r];
        if (t1v) {
            #pragma unroll
            for (int r = 0; r < 4; ++r)
                Cout[(size_t)(mt1 + quad * 4 + r) * NC + c] = (_Float16)v1[r];
        }
        if (STATS) {
            float s = v0[0] + v0[1] + v0[2] + v0[3];
            float q = v0[0]*v0[0] + v0[1]*v0[1] + v0[2]*v0[2] + v0[3]*v0[3];
            if (t1v) {
                s += v1[0] + v1[1] + v1[2] + v1[3];
                q += v1[0]*v1[0] + v1[1]*v1[1] + v1[2]*v1[2] + v1[3]*v1[3];
            }
            s += __shfl_xor(s, 16, 64); s += __shfl_xor(s, 32, 64);
            q += __shfl_xor(q, 16, 64); q += __shfl_xor(q, 32, 64);
            if (lane < 16) {
                atomicAdd(&osum[c], s);
                atomicAdd(&osq[c], q);
            }
        }
    }
}

template <int C>
__global__ void bn_finalize(const float* __restrict__ ssum, const float* __restrict__ ssq,
                            const float* __restrict__ g, const float* __restrict__ b,
                            float* __restrict__ scale, float* __restrict__ shift) {
    int c = threadIdx.x;
    float mean = ssum[c] * (1.0f / N_NODES);
    float var = ssq[c] * (1.0f / N_NODES) - mean * mean;
    float sc = g[c] * rsqrtf(var + 1e-5f);
    scale[c] = sc;
    shift[c] = b[c] - mean * sc;
}

// ---------------- pooling ----------------
__global__ void count_graph(const int* __restrict__ batch, int* __restrict__ gcnt) {
    int n = blockIdx.x * 256 + threadIdx.x;
    if (n < N_NODES) atomicAdd(&gcnt[batch[n]], 1);
}

__global__ void scan_g(const int* __restrict__ gcnt, int* __restrict__ gptr) {
    __shared__ int s[512];
    int v = gcnt[threadIdx.x];
    s[threadIdx.x] = v;
    __syncthreads();
    for (int off = 1; off < 512; off <<= 1) {
        int t = (threadIdx.x >= off) ? s[threadIdx.x - off] : 0;
        __syncthreads();
        s[threadIdx.x] += t;
        __syncthreads();
    }
    gptr[threadIdx.x] = s[threadIdx.x] - v;
    if (threadIdx.x == 511) gptr[512] = s[511];
}

__global__ void pool16(const _Float16* __restrict__ h, const int* __restrict__ gptr,
                       float* __restrict__ hg) {
    int g = blockIdx.x;
    int lane = threadIdx.x;
    int n0 = gptr[g], n1 = gptr[g + 1];
    float2 acc = {0.f, 0.f};
    for (int n = n0; n < n1; ++n) {
        f16x2 v = ((const f16x2*)(h + (size_t)n * DIM))[lane];
        acc.x += (float)v[0]; acc.y += (float)v[1];
    }
    float inv = 1.0f / fmaxf((float)(n1 - n0), 1.0f);
    float2 r; r.x = acc.x * inv; r.y = acc.y * inv;
    ((float2*)(hg + (size_t)g * DIM))[lane] = r;
}

__global__ void outk(const float* __restrict__ hg, const float* __restrict__ Wout,
                     const float* __restrict__ bout, float* __restrict__ out) {
    __shared__ float s[DIM];
    int g = blockIdx.x;
    for (int d = threadIdx.x; d < DIM; d += 64) s[d] = hg[(size_t)g * DIM + d];
    __syncthreads();
    int t = threadIdx.x;
    if (t < TDIM) {
        float acc = bout[t];
        for (int d = 0; d < DIM; ++d) acc += s[d] * Wout[d * TDIM + t];
        out[g * TDIM + t] = acc;
    }
}

extern "C" void kernel_launch(void* const* d_in, const int* in_sizes, int n_in,
                              void* d_out, int out_size, void* d_ws, size_t ws_size,
                              hipStream_t stream) {
    const int*   x     = (const int*)d_in[0];
    const int*   ei    = (const int*)d_in[1];
    const int*   batch = (const int*)d_in[2];
    const float* emb   = (const float*)d_in[3];
    const float* W1    = (const float*)d_in[4];
    const float* b1    = (const float*)d_in[5];
    const float* g1    = (const float*)d_in[6];
    const float* be1   = (const float*)d_in[7];
    const float* W2    = (const float*)d_in[8];
    const float* b2    = (const float*)d_in[9];
    const float* epsA  = (const float*)d_in[10];
    const float* bng   = (const float*)d_in[11];
    const float* bnb   = (const float*)d_in[12];
    const float* Wout  = (const float*)d_in[13];
    const float* bout  = (const float*)d_in[14];
    float* out = (float*)d_out;

    const int* srcIdx = ei;
    const int* dstIdx = ei + N_EDGES;

    char* base = (char*)d_ws;
    size_t off = 0;
    auto alloc = [&](size_t bytes) {
        char* p = base + off;
        off = (off + bytes + 255) & ~(size_t)255;
        return p;
    };
    _Float16* hraw  = (_Float16*)alloc((size_t)N_NODES * DIM * 2);
    _Float16* hrel  = (_Float16*)alloc((size_t)N_NODES * DIM * 2);   // layer-0 gather input
    _Float16* agg   = (_Float16*)alloc((size_t)N_NODES * DIM * 2);
    _Float16* z16   = (_Float16*)alloc((size_t)N_NODES * DIM2 * 2);
    _Float16* h2    = (_Float16*)alloc((size_t)N_NODES * DIM * 2);
    _Float16* W1t   = (_Float16*)alloc((size_t)NLAYER * DIM * DIM2 * 2);
    _Float16* W2t   = (_Float16*)alloc((size_t)NLAYER * DIM * DIM2 * 2);
    int*   rp    = (int*)alloc((N_NODES + 1) * 4);
    int*   tmpN  = (int*)alloc(N_NODES * 4);
    int*   col   = (int*)alloc(N_EDGES * 4);
    int*   bsum  = (int*)alloc(128 * 4);
    int*   boff  = (int*)alloc(128 * 4);
    int*   gcnt  = (int*)alloc(NGRAPH * 4);
    int*   gptr  = (int*)alloc((NGRAPH + 1) * 4);
    float* stats = (float*)alloc(768 * 4);     // [ssum1:256][ssq1:256][ssum2:128][ssq2:128]
    float* scl1  = (float*)alloc(DIM2 * 4);
    float* sft1  = (float*)alloc(DIM2 * 4);
    float* scl2  = (float*)alloc(DIM * 4);
    float* sft2  = (float*)alloc(DIM * 4);
    float* hg    = (float*)alloc((size_t)NGRAPH * DIM * 4);

    float* ssum1 = stats, *ssq1 = stats + 256, *ssum2 = stats + 512, *ssq2 = stats + 640;

    convert_w<<<(NLAYER * DIM * DIM2 + 255) / 256, 256, 0, stream>>>(W1, W2, W1t, W2t);
    atom_encoder<<<N_NODES / 4, 256, 0, stream>>>(x, emb, hraw, hrel);

    // CSR build (reused by all 5 layers)
    hipMemsetAsync(tmpN, 0, N_NODES * 4, stream);
    count_deg<<<(N_EDGES + 255) / 256, 256, 0, stream>>>(dstIdx, tmpN);
    scan_a<<<98, 512, 0, stream>>>(tmpN, rp, bsum);
    scan_b<<<1, 128, 0, stream>>>(bsum, boff);
    scan_c<<<98, 512, 0, stream>>>(rp, boff);
    hipMemsetAsync(tmpN, 0, N_NODES * 4, stream);
    fill_csr<<<(N_EDGES + 255) / 256, 256, 0, stream>>>(srcIdx, dstIdx, rp, tmpN, col);

    // graph pooling CSR
    hipMemsetAsync(gcnt, 0, NGRAPH * 4, stream);
    count_graph<<<(N_NODES + 255) / 256, 256, 0, stream>>>(batch, gcnt);
    scan_g<<<1, 512, 0, stream>>>(gcnt, gptr);

    const int GG = (N_NODES + 127) / 128;   // 391

    for (int i = 0; i < NLAYER; ++i) {
        if (i == 0)
            gather_agg<0><<<N_NODES / 4, 256, 0, stream>>>(hrel, rp, col, nullptr, nullptr, agg);
        else
            gather_agg<1><<<N_NODES / 4, 256, 0, stream>>>(h2, rp, col, scl2, sft2, agg);

        hipMemsetAsync(stats, 0, 768 * 4, stream);

        if (i == 0)
            gemm_mfma<128, 256, 0, 0, 1><<<GG, 256, 0, stream>>>(
                hraw, agg, W1t, b1, nullptr, nullptr, epsA, 0, z16, ssum1, ssq1);
        else
            gemm_mfma<128, 256, 0, 1, 1><<<GG, 256, 0, stream>>>(
                h2, agg, W1t + (size_t)i * DIM * DIM2, b1 + i * 256,
                scl2, sft2, epsA, i, z16, ssum1, ssq1);

        bn_finalize<256><<<1, 256, 0, stream>>>(ssum1, ssq1, g1 + i * 256, be1 + i * 256, scl1, sft1);

        if (i < NLAYER - 1) {
            gemm_mfma<256, 128, 1, 0, 1><<<GG, 256, 0, stream>>>(
                z16, nullptr, W2t + (size_t)i * DIM * DIM2, b2 + i * 128,
                scl1, sft1, epsA, i, h2, ssum2, ssq2);
            bn_finalize<128><<<1, 128, 0, stream>>>(ssum2, ssq2, bng + i * 128, bnb + i * 128, scl2, sft2);
        } else {
            gemm_mfma<256, 128, 1, 0, 0><<<GG, 256, 0, stream>>>(
                z16, nullptr, W2t + (size_t)i * DIM * DIM2, b2 + i * 128,
                scl1, sft1, epsA, i, h2, ssum2, ssq2);
        }
    }

    pool16<<<NGRAPH, 64, 0, stream>>>(h2, gptr, hg);
    outk<<<NGRAPH, 64, 0, stream>>>(hg, Wout, bout, out);
}

// Round 4
// 1220.396 us; speedup vs baseline: 1.7008x; 1.2026x over previous
//
#include <hip/hip_runtime.h>
#include <hip/hip_bf16.h>

#define N_NODES 50000
#define N_EDGES 800000
#define DIM     128
#define DIM2    256
#define NLAYER  5
#define NGRAPH  512
#define TDIM    10
#define VMAX    119

typedef _Float16 f16x8 __attribute__((ext_vector_type(8)));
typedef _Float16 f16x2 __attribute__((ext_vector_type(2)));
typedef float    f32x4 __attribute__((ext_vector_type(4)));

// ---------------- weight convert + transpose to f16 [n][k] ----------------
__global__ void convert_w(const float* __restrict__ W1, const float* __restrict__ W2,
                          _Float16* __restrict__ W1t, _Float16* __restrict__ W2t) {
    int idx = blockIdx.x * 256 + threadIdx.x;
    if (idx >= NLAYER * DIM * DIM2) return;
    int l = idx / (DIM * DIM2);
    int rem = idx % (DIM * DIM2);
    int k1 = rem / DIM2, n1 = rem % DIM2;
    W1t[(size_t)l * DIM * DIM2 + (size_t)n1 * DIM + k1] = (_Float16)W1[idx];
    int k2 = rem / DIM, n2 = rem % DIM;
    W2t[(size_t)l * DIM * DIM2 + (size_t)n2 * DIM2 + k2] = (_Float16)W2[idx];
}

// ---------------- atom encoder -> hraw f16 (GEMM1 layer0 A), hrel f16 (layer0 gather) ---
__global__ void atom_encoder(const int* __restrict__ x, const float* __restrict__ emb,
                             _Float16* __restrict__ hraw, _Float16* __restrict__ hrelu) {
    int node = blockIdx.x * 4 + (threadIdx.x >> 6);
    int lane = threadIdx.x & 63;
    if (node >= N_NODES) return;
    float2 acc = {0.f, 0.f};
    const int* xr = x + node * 9;
    #pragma unroll
    for (int t = 0; t < 9; ++t) {
        int v = xr[t];
        const float2* row = (const float2*)(emb + ((size_t)t * VMAX + v) * DIM);
        float2 e = row[lane];
        acc.x += e.x; acc.y += e.y;
    }
    f16x2 o, orl;
    o[0] = (_Float16)acc.x; o[1] = (_Float16)acc.y;
    orl[0] = (_Float16)fmaxf(acc.x, 0.f); orl[1] = (_Float16)fmaxf(acc.y, 0.f);
    ((f16x2*)(hraw + (size_t)node * DIM))[lane] = o;
    ((f16x2*)(hrelu + (size_t)node * DIM))[lane] = orl;
}

// ---------------- CSR build ----------------
__global__ void count_deg(const int* __restrict__ dst, int* __restrict__ deg) {
    int e = blockIdx.x * blockDim.x + threadIdx.x;
    if (e < N_EDGES) atomicAdd(&deg[dst[e]], 1);
}

__global__ void scan_a(const int* __restrict__ deg, int* __restrict__ rp, int* __restrict__ bsum) {
    __shared__ int s[512];
    int i = blockIdx.x * 512 + threadIdx.x;
    int v = (i < N_NODES) ? deg[i] : 0;
    s[threadIdx.x] = v;
    __syncthreads();
    for (int off = 1; off < 512; off <<= 1) {
        int t = (threadIdx.x >= off) ? s[threadIdx.x - off] : 0;
        __syncthreads();
        s[threadIdx.x] += t;
        __syncthreads();
    }
    if (i < N_NODES) rp[i] = s[threadIdx.x] - v;   // exclusive
    if (threadIdx.x == 511) bsum[blockIdx.x] = s[511];
}

__global__ void scan_b(const int* __restrict__ bsum, int* __restrict__ boff) {
    __shared__ int s[128];
    const int NB = 98;
    int v = (threadIdx.x < NB) ? bsum[threadIdx.x] : 0;
    s[threadIdx.x] = v;
    __syncthreads();
    for (int off = 1; off < 128; off <<= 1) {
        int t = (threadIdx.x >= off) ? s[threadIdx.x - off] : 0;
        __syncthreads();
        s[threadIdx.x] += t;
        __syncthreads();
    }
    if (threadIdx.x < NB) boff[threadIdx.x] = s[threadIdx.x] - v;
}

__global__ void scan_c(int* __restrict__ rp, const int* __restrict__ boff) {
    int i = blockIdx.x * 512 + threadIdx.x;
    if (i < N_NODES) rp[i] += boff[blockIdx.x];
    if (blockIdx.x == 0 && threadIdx.x == 0) rp[N_NODES] = N_EDGES;
}

__global__ void fill_csr(const int* __restrict__ src, const int* __restrict__ dst,
                         const int* __restrict__ rp, int* __restrict__ cursor,
                         int* __restrict__ col) {
    int e = blockIdx.x * blockDim.x + threadIdx.x;
    if (e < N_EDGES) {
        int d = dst[e];
        int pos = atomicAdd(&cursor[d], 1);
        col[rp[d] + pos] = src[e];
    }
}

// -------- aggregation. APPLY_BN=0: rows already relu'd. APPLY_BN=1: relu(v*sc+sh) ------
template <int APPLY_BN>
__global__ void gather_agg(const _Float16* __restrict__ hsrc, const int* __restrict__ rp,
                           const int* __restrict__ col, const float* __restrict__ scale,
                           const float* __restrict__ shift, _Float16* __restrict__ agg) {
    int node = blockIdx.x * 4 + (threadIdx.x >> 6);
    int lane = threadIdx.x & 63;
    if (node >= N_NODES) return;
    float sc0 = 0.f, sc1 = 0.f, sh0 = 0.f, sh1 = 0.f;
    if (APPLY_BN) {
        sc0 = scale[lane * 2]; sc1 = scale[lane * 2 + 1];
        sh0 = shift[lane * 2]; sh1 = shift[lane * 2 + 1];
    }
    int e0 = rp[node], e1 = rp[node + 1];
    float2 acc = {0.f, 0.f};
    for (int e = e0; e < e1; ++e) {
        int s = col[e];
        f16x2 v = ((const f16x2*)(hsrc + (size_t)s * DIM))[lane];
        float a = (float)v[0], b = (float)v[1];
        if (APPLY_BN) {
            a = fmaxf(a * sc0 + sh0, 0.f);
            b = fmaxf(b * sc1 + sh1, 0.f);
        }
        acc.x += a; acc.y += b;
    }
    f16x2 o;
    o[0] = (_Float16)acc.x; o[1] = (_Float16)acc.y;
    ((f16x2*)(agg + (size_t)node * DIM))[lane] = o;
}

// ---------------- MFMA GEMM, register-held B, no LDS, fused BN-stats epilogue ----------
// Block = 4 waves, 32 rows. Wave w owns cols [w*NC/4, (w+1)*NC/4).
// MODE 0: A[m][k] = (1+eps) * f(A0[m][k]) + A1[m][k], f = BN-relu if APPLY_BN else id
// MODE 1: A[m][k] = relu(A0[m][k]*scale[k] + shift[k])
// Bt f16 [NC][K], L2-broadcast. Stats: osum/osq += column sums/sumsq of C.
template <int K, int NC, int MODE, int APPLY_BN, int STATS>
__global__ __launch_bounds__(256) void gemm_mfma(
    const _Float16* __restrict__ A0h, const _Float16* __restrict__ A1h,
    const _Float16* __restrict__ Bt, const float* __restrict__ bias,
    const float* __restrict__ scale, const float* __restrict__ shift,
    const float* __restrict__ epsArr, int layer, _Float16* __restrict__ Cout,
    float* __restrict__ osum, float* __restrict__ osq) {
    const int WC = NC / 4;        // cols per wave (64 or 32)
    const int NT = WC / 16;       // 16-col tiles per wave (4 or 2)
    const int KI = K / 32;        // k-steps (4 or 8)
    int tid = threadIdx.x;
    int wave = tid >> 6, lane = tid & 63, quad = lane >> 4, l16 = lane & 15;
    int n0 = wave * WC;

    // B fragments in registers, loaded once (same data across blocks -> L2 hits)
    f16x8 bfrag[NT][KI];
    #pragma unroll
    for (int nt = 0; nt < NT; ++nt)
        #pragma unroll
        for (int kt = 0; kt < KI; ++kt)
            bfrag[nt][kt] = *(const f16x8*)(Bt + (size_t)(n0 + nt * 16 + l16) * K + kt * 32 + quad * 8);

    int m0 = blockIdx.x * 32;          // always < N_NODES (1563*32 > 50000 > 1562*32)
    int mt1 = m0 + 16;
    bool t1v = (mt1 < N_NODES);        // 50000 % 16 == 0: tiles fully valid or fully invalid
    int mrow0 = m0 + l16;
    int mrow1 = t1v ? (mt1 + l16) : mrow0;

    f32x4 acc0[NT], acc1[NT];
    #pragma unroll
    for (int nt = 0; nt < NT; ++nt) { acc0[nt] = (f32x4){0,0,0,0}; acc1[nt] = (f32x4){0,0,0,0}; }
    float evf = (MODE == 0) ? (1.0f + epsArr[layer]) : 0.0f;

    #pragma unroll
    for (int kt = 0; kt < KI; ++kt) {
        int kb = kt * 32 + quad * 8;
        f32x4 sc0v, sc1v, sh0v, sh1v;
        if (MODE == 1 || APPLY_BN) {
            sc0v = *(const f32x4*)(scale + kb); sc1v = *(const f32x4*)(scale + kb + 4);
            sh0v = *(const f32x4*)(shift + kb); sh1v = *(const f32x4*)(shift + kb + 4);
        }
        f16x8 afrag0, afrag1;
        if (MODE == 0) {
            f16x8 h0 = *(const f16x8*)(A0h + (size_t)mrow0 * K + kb);
            f16x8 h1 = *(const f16x8*)(A0h + (size_t)mrow1 * K + kb);
            f16x8 a0 = *(const f16x8*)(A1h + (size_t)mrow0 * K + kb);
            f16x8 a1 = *(const f16x8*)(A1h + (size_t)mrow1 * K + kb);
            #pragma unroll
            for (int j = 0; j < 8; ++j) {
                float f0 = (float)h0[j], f1 = (float)h1[j];
                if (APPLY_BN) {
                    float sc = (j < 4) ? sc0v[j & 3] : sc1v[j & 3];
                    float sh = (j < 4) ? sh0v[j & 3] : sh1v[j & 3];
                    f0 = fmaxf(f0 * sc + sh, 0.f);
                    f1 = fmaxf(f1 * sc + sh, 0.f);
                }
                afrag0[j] = (_Float16)(evf * f0 + (float)a0[j]);
                afrag1[j] = (_Float16)(evf * f1 + (float)a1[j]);
            }
        } else {
            f16x8 z0 = *(const f16x8*)(A0h + (size_t)mrow0 * K + kb);
            f16x8 z1 = *(const f16x8*)(A0h + (size_t)mrow1 * K + kb);
            #pragma unroll
            for (int j = 0; j < 8; ++j) {
                float sc = (j < 4) ? sc0v[j & 3] : sc1v[j & 3];
                float sh = (j < 4) ? sh0v[j & 3] : sh1v[j & 3];
                afrag0[j] = (_Float16)fmaxf((float)z0[j] * sc + sh, 0.f);
                afrag1[j] = (_Float16)fmaxf((float)z1[j] * sc + sh, 0.f);
            }
        }
        #pragma unroll
        for (int nt = 0; nt < NT; ++nt) {
            acc0[nt] = __builtin_amdgcn_mfma_f32_16x16x32_f16(afrag0, bfrag[nt][kt], acc0[nt], 0, 0, 0);
            acc1[nt] = __builtin_amdgcn_mfma_f32_16x16x32_f16(afrag1, bfrag[nt][kt], acc1[nt], 0, 0, 0);
        }
    }

    // epilogue: C layout col = l16, row = quad*4 + r
    #pragma unroll
    for (int nt = 0; nt < NT; ++nt) {
        int c = n0 + nt * 16 + l16;
        float bv = bias[c];
        float v0[4], v1[4];
        #pragma unroll
        for (int r = 0; r < 4; ++r) { v0[r] = acc0[nt][r] + bv; v1[r] = acc1[nt][r] + bv; }
        #pragma unroll
        for (int r = 0; r < 4; ++r)
            Cout[(size_t)(m0 + quad * 4 + r) * NC + c] = (_Float16)v0[r];
        if (t1v) {
            #pragma unroll
            for (int r = 0; r < 4; ++r)
                Cout[(size_t)(mt1 + quad * 4 + r) * NC + c] = (_Float16)v1[r];
        }
        if (STATS) {
            float s = v0[0] + v0[1] + v0[2] + v0[3];
            float q = v0[0]*v0[0] + v0[1]*v0[1] + v0[2]*v0[2] + v0[3]*v0[3];
            if (t1v) {
                s += v1[0] + v1[1] + v1[2] + v1[3];
                q += v1[0]*v1[0] + v1[1]*v1[1] + v1[2]*v1[2] + v1[3]*v1[3];
            }
            s += __shfl_xor(s, 16, 64); s += __shfl_xor(s, 32, 64);
            q += __shfl_xor(q, 16, 64); q += __shfl_xor(q, 32, 64);
            if (lane < 16) {
                atomicAdd(&osum[c], s);
                atomicAdd(&osq[c], q);
            }
        }
    }
}

template <int C>
__global__ void bn_finalize(const float* __restrict__ ssum, const float* __restrict__ ssq,
                            const float* __restrict__ g, const float* __restrict__ b,
                            float* __restrict__ scale, float* __restrict__ shift) {
    int c = threadIdx.x;
    float mean = ssum[c] * (1.0f / N_NODES);
    float var = ssq[c] * (1.0f / N_NODES) - mean * mean;
    float sc = g[c] * rsqrtf(var + 1e-5f);
    scale[c] = sc;
    shift[c] = b[c] - mean * sc;
}

// ---------------- pooling ----------------
__global__ void count_graph(const int* __restrict__ batch, int* __restrict__ gcnt) {
    int n = blockIdx.x * 256 + threadIdx.x;
    if (n < N_NODES) atomicAdd(&gcnt[batch[n]], 1);
}

__global__ void scan_g(const int* __restrict__ gcnt, int* __restrict__ gptr) {
    __shared__ int s[512];
    int v = gcnt[threadIdx.x];
    s[threadIdx.x] = v;
    __syncthreads();
    for (int off = 1; off < 512; off <<= 1) {
        int t = (threadIdx.x >= off) ? s[threadIdx.x - off] : 0;
        __syncthreads();
        s[threadIdx.x] += t;
        __syncthreads();
    }
    gptr[threadIdx.x] = s[threadIdx.x] - v;
    if (threadIdx.x == 511) gptr[512] = s[511];
}

__global__ void pool16(const _Float16* __restrict__ h, const int* __restrict__ gptr,
                       float* __restrict__ hg) {
    int g = blockIdx.x;
    int lane = threadIdx.x;
    int n0 = gptr[g], n1 = gptr[g + 1];
    float2 acc = {0.f, 0.f};
    for (int n = n0; n < n1; ++n) {
        f16x2 v = ((const f16x2*)(h + (size_t)n * DIM))[lane];
        acc.x += (float)v[0]; acc.y += (float)v[1];
    }
    float inv = 1.0f / fmaxf((float)(n1 - n0), 1.0f);
    float2 r; r.x = acc.x * inv; r.y = acc.y * inv;
    ((float2*)(hg + (size_t)g * DIM))[lane] = r;
}

__global__ void outk(const float* __restrict__ hg, const float* __restrict__ Wout,
                     const float* __restrict__ bout, float* __restrict__ out) {
    __shared__ float s[DIM];
    int g = blockIdx.x;
    for (int d = threadIdx.x; d < DIM; d += 64) s[d] = hg[(size_t)g * DIM + d];
    __syncthreads();
    int t = threadIdx.x;
    if (t < TDIM) {
        float acc = bout[t];
        for (int d = 0; d < DIM; ++d) acc += s[d] * Wout[d * TDIM + t];
        out[g * TDIM + t] = acc;
    }
}

extern "C" void kernel_launch(void* const* d_in, const int* in_sizes, int n_in,
                              void* d_out, int out_size, void* d_ws, size_t ws_size,
                              hipStream_t stream) {
    const int*   x     = (const int*)d_in[0];
    const int*   ei    = (const int*)d_in[1];
    const int*   batch = (const int*)d_in[2];
    const float* emb   = (const float*)d_in[3];
    const float* W1    = (const float*)d_in[4];
    const float* b1    = (const float*)d_in[5];
    const float* g1    = (const float*)d_in[6];
    const float* be1   = (const float*)d_in[7];
    const float* W2    = (const float*)d_in[8];
    const float* b2    = (const float*)d_in[9];
    const float* epsA  = (const float*)d_in[10];
    const float* bng   = (const float*)d_in[11];
    const float* bnb   = (const float*)d_in[12];
    const float* Wout  = (const float*)d_in[13];
    const float* bout  = (const float*)d_in[14];
    float* out = (float*)d_out;

    const int* srcIdx = ei;
    const int* dstIdx = ei + N_EDGES;

    char* base = (char*)d_ws;
    size_t off = 0;
    auto alloc = [&](size_t bytes) {
        char* p = base + off;
        off = (off + bytes + 255) & ~(size_t)255;
        return p;
    };
    _Float16* hraw  = (_Float16*)alloc((size_t)N_NODES * DIM * 2);
    _Float16* hrel  = (_Float16*)alloc((size_t)N_NODES * DIM * 2);   // layer-0 gather input
    _Float16* agg   = (_Float16*)alloc((size_t)N_NODES * DIM * 2);
    _Float16* z16   = (_Float16*)alloc((size_t)N_NODES * DIM2 * 2);
    _Float16* h2    = (_Float16*)alloc((size_t)N_NODES * DIM * 2);
    _Float16* W1t   = (_Float16*)alloc((size_t)NLAYER * DIM * DIM2 * 2);
    _Float16* W2t   = (_Float16*)alloc((size_t)NLAYER * DIM * DIM2 * 2);
    int*   rp    = (int*)alloc((N_NODES + 1) * 4);
    int*   tmpN  = (int*)alloc(N_NODES * 4);
    int*   col   = (int*)alloc(N_EDGES * 4);
    int*   bsum  = (int*)alloc(128 * 4);
    int*   boff  = (int*)alloc(128 * 4);
    int*   gcnt  = (int*)alloc(NGRAPH * 4);
    int*   gptr  = (int*)alloc((NGRAPH + 1) * 4);
    float* stats = (float*)alloc(768 * 4);     // [ssum1:256][ssq1:256][ssum2:128][ssq2:128]
    float* scl1  = (float*)alloc(DIM2 * 4);
    float* sft1  = (float*)alloc(DIM2 * 4);
    float* scl2  = (float*)alloc(DIM * 4);
    float* sft2  = (float*)alloc(DIM * 4);
    float* hg    = (float*)alloc((size_t)NGRAPH * DIM * 4);

    float* ssum1 = stats, *ssq1 = stats + 256, *ssum2 = stats + 512, *ssq2 = stats + 640;

    convert_w<<<(NLAYER * DIM * DIM2 + 255) / 256, 256, 0, stream>>>(W1, W2, W1t, W2t);
    atom_encoder<<<N_NODES / 4, 256, 0, stream>>>(x, emb, hraw, hrel);

    // CSR build (reused by all 5 layers)
    hipMemsetAsync(tmpN, 0, N_NODES * 4, stream);
    count_deg<<<(N_EDGES + 255) / 256, 256, 0, stream>>>(dstIdx, tmpN);
    scan_a<<<98, 512, 0, stream>>>(tmpN, rp, bsum);
    scan_b<<<1, 128, 0, stream>>>(bsum, boff);
    scan_c<<<98, 512, 0, stream>>>(rp, boff);
    hipMemsetAsync(tmpN, 0, N_NODES * 4, stream);
    fill_csr<<<(N_EDGES + 255) / 256, 256, 0, stream>>>(srcIdx, dstIdx, rp, tmpN, col);

    // graph pooling CSR
    hipMemsetAsync(gcnt, 0, NGRAPH * 4, stream);
    count_graph<<<(N_NODES + 255) / 256, 256, 0, stream>>>(batch, gcnt);
    scan_g<<<1, 512, 0, stream>>>(gcnt, gptr);

    const int GG = (N_NODES + 31) / 32;   // 1563 blocks

    for (int i = 0; i < NLAYER; ++i) {
        if (i == 0)
            gather_agg<0><<<N_NODES / 4, 256, 0, stream>>>(hrel, rp, col, nullptr, nullptr, agg);
        else
            gather_agg<1><<<N_NODES / 4, 256, 0, stream>>>(h2, rp, col, scl2, sft2, agg);

        hipMemsetAsync(stats, 0, 768 * 4, stream);

        if (i == 0)
            gemm_mfma<128, 256, 0, 0, 1><<<GG, 256, 0, stream>>>(
                hraw, agg, W1t, b1, nullptr, nullptr, epsA, 0, z16, ssum1, ssq1);
        else
            gemm_mfma<128, 256, 0, 1, 1><<<GG, 256, 0, stream>>>(
                h2, agg, W1t + (size_t)i * DIM * DIM2, b1 + i * 256,
                scl2, sft2, epsA, i, z16, ssum1, ssq1);

        bn_finalize<256><<<1, 256, 0, stream>>>(ssum1, ssq1, g1 + i * 256, be1 + i * 256, scl1, sft1);

        if (i < NLAYER - 1) {
            gemm_mfma<256, 128, 1, 0, 1><<<GG, 256, 0, stream>>>(
                z16, nullptr, W2t + (size_t)i * DIM * DIM2, b2 + i * 128,
                scl1, sft1, epsA, i, h2, ssum2, ssq2);
            bn_finalize<128><<<1, 128, 0, stream>>>(ssum2, ssq2, bng + i * 128, bnb + i * 128, scl2, sft2);
        } else {
            gemm_mfma<256, 128, 1, 0, 0><<<GG, 256, 0, stream>>>(
                z16, nullptr, W2t + (size_t)i * DIM * DIM2, b2 + i * 128,
                scl1, sft1, epsA, i, h2, ssum2, ssq2);
        }
    }

    pool16<<<NGRAPH, 64, 0, stream>>>(h2, gptr, hg);
    outk<<<NGRAPH, 64, 0, stream>>>(hg, Wout, bout, out);
}

// Round 5
// 989.647 us; speedup vs baseline: 2.0973x; 1.2332x over previous
//
#include <hip/hip_runtime.h>
#include <hip/hip_bf16.h>

#define N_NODES 50000
#define N_EDGES 800000
#define DIM     128
#define DIM2    256
#define NLAYER  5
#define NGRAPH  512
#define TDIM    10
#define VMAX    119

typedef _Float16 f16x8 __attribute__((ext_vector_type(8)));
typedef _Float16 f16x2 __attribute__((ext_vector_type(2)));
typedef float    f32x4 __attribute__((ext_vector_type(4)));

static __device__ inline f16x8 relu8(f16x8 v) {
#if __has_builtin(__builtin_elementwise_max)
    return __builtin_elementwise_max(v, (f16x8){0, 0, 0, 0, 0, 0, 0, 0});
#else
    #pragma unroll
    for (int j = 0; j < 8; ++j) v[j] = v[j] > (_Float16)0 ? v[j] : (_Float16)0;
    return v;
#endif
}

static __device__ inline f16x2 relu2(f16x2 v) {
#if __has_builtin(__builtin_elementwise_max)
    return __builtin_elementwise_max(v, (f16x2){0, 0});
#else
    #pragma unroll
    for (int j = 0; j < 2; ++j) v[j] = v[j] > (_Float16)0 ? v[j] : (_Float16)0;
    return v;
#endif
}

// ---------------- weight convert + transpose to f16 [n][k] ----------------
__global__ void convert_w(const float* __restrict__ W1, const float* __restrict__ W2,
                          _Float16* __restrict__ W1t, _Float16* __restrict__ W2t) {
    int idx = blockIdx.x * 256 + threadIdx.x;
    if (idx >= NLAYER * DIM * DIM2) return;
    int l = idx / (DIM * DIM2);
    int rem = idx % (DIM * DIM2);
    int k1 = rem / DIM2, n1 = rem % DIM2;
    W1t[(size_t)l * DIM * DIM2 + (size_t)n1 * DIM + k1] = (_Float16)W1[idx];
    int k2 = rem / DIM, n2 = rem % DIM;
    W2t[(size_t)l * DIM * DIM2 + (size_t)n2 * DIM2 + k2] = (_Float16)W2[idx];
}

// ---------------- atom encoder -> hraw f16 (GEMM1 layer0 A), hrel f16 (layer0 gather) ---
__global__ void atom_encoder(const int* __restrict__ x, const float* __restrict__ emb,
                             _Float16* __restrict__ hraw, _Float16* __restrict__ hrelu) {
    int node = blockIdx.x * 4 + (threadIdx.x >> 6);
    int lane = threadIdx.x & 63;
    if (node >= N_NODES) return;
    float2 acc = {0.f, 0.f};
    const int* xr = x + node * 9;
    #pragma unroll
    for (int t = 0; t < 9; ++t) {
        int v = xr[t];
        const float2* row = (const float2*)(emb + ((size_t)t * VMAX + v) * DIM);
        float2 e = row[lane];
        acc.x += e.x; acc.y += e.y;
    }
    f16x2 o, orl;
    o[0] = (_Float16)acc.x; o[1] = (_Float16)acc.y;
    orl[0] = (_Float16)fmaxf(acc.x, 0.f); orl[1] = (_Float16)fmaxf(acc.y, 0.f);
    ((f16x2*)(hraw + (size_t)node * DIM))[lane] = o;
    ((f16x2*)(hrelu + (size_t)node * DIM))[lane] = orl;
}

// ---------------- CSR build ----------------
__global__ void count_deg(const int* __restrict__ dst, int* __restrict__ deg) {
    int e = blockIdx.x * blockDim.x + threadIdx.x;
    if (e < N_EDGES) atomicAdd(&deg[dst[e]], 1);
}

__global__ void scan_a(const int* __restrict__ deg, int* __restrict__ rp, int* __restrict__ bsum) {
    __shared__ int s[512];
    int i = blockIdx.x * 512 + threadIdx.x;
    int v = (i < N_NODES) ? deg[i] : 0;
    s[threadIdx.x] = v;
    __syncthreads();
    for (int off = 1; off < 512; off <<= 1) {
        int t = (threadIdx.x >= off) ? s[threadIdx.x - off] : 0;
        __syncthreads();
        s[threadIdx.x] += t;
        __syncthreads();
    }
    if (i < N_NODES) rp[i] = s[threadIdx.x] - v;   // exclusive
    if (threadIdx.x == 511) bsum[blockIdx.x] = s[511];
}

__global__ void scan_b(const int* __restrict__ bsum, int* __restrict__ boff) {
    __shared__ int s[128];
    const int NB = 98;
    int v = (threadIdx.x < NB) ? bsum[threadIdx.x] : 0;
    s[threadIdx.x] = v;
    __syncthreads();
    for (int off = 1; off < 128; off <<= 1) {
        int t = (threadIdx.x >= off) ? s[threadIdx.x - off] : 0;
        __syncthreads();
        s[threadIdx.x] += t;
        __syncthreads();
    }
    if (threadIdx.x < NB) boff[threadIdx.x] = s[threadIdx.x] - v;
}

__global__ void scan_c(int* __restrict__ rp, const int* __restrict__ boff) {
    int i = blockIdx.x * 512 + threadIdx.x;
    if (i < N_NODES) rp[i] += boff[blockIdx.x];
    if (blockIdx.x == 0 && threadIdx.x == 0) rp[N_NODES] = N_EDGES;
}

__global__ void fill_csr(const int* __restrict__ src, const int* __restrict__ dst,
                         const int* __restrict__ rp, int* __restrict__ cursor,
                         int* __restrict__ col) {
    int e = blockIdx.x * blockDim.x + threadIdx.x;
    if (e < N_EDGES) {
        int d = dst[e];
        int pos = atomicAdd(&cursor[d], 1);
        col[rp[d] + pos] = src[e];
    }
}

// -------- aggregation, unroll-8 for MLP. APPLY_BN=1: rows get relu(v*sc+sh) (f16 pk) ---
template <int APPLY_BN>
__global__ void gather_agg(const _Float16* __restrict__ hsrc, const int* __restrict__ rp,
                           const int* __restrict__ col, const _Float16* __restrict__ scale16,
                           const _Float16* __restrict__ shift16, _Float16* __restrict__ agg) {
    int node = blockIdx.x * 4 + (threadIdx.x >> 6);
    int lane = threadIdx.x & 63;
    if (node >= N_NODES) return;
    f16x2 sc = {0, 0}, sh = {0, 0};
    if (APPLY_BN) {
        sc = ((const f16x2*)scale16)[lane];
        sh = ((const f16x2*)shift16)[lane];
    }
    int e0 = rp[node], e1 = rp[node + 1];
    float2 acc = {0.f, 0.f};
    int e = e0;
    for (; e + 8 <= e1; e += 8) {
        int idx[8];
        #pragma unroll
        for (int j = 0; j < 8; ++j) idx[j] = col[e + j];
        f16x2 v[8];
        #pragma unroll
        for (int j = 0; j < 8; ++j)
            v[j] = ((const f16x2*)(hsrc + (size_t)idx[j] * DIM))[lane];
        #pragma unroll
        for (int j = 0; j < 8; ++j) {
            f16x2 w = v[j];
            if (APPLY_BN) w = relu2(w * sc + sh);
            acc.x += (float)w[0]; acc.y += (float)w[1];
        }
    }
    for (; e < e1; ++e) {
        f16x2 w = ((const f16x2*)(hsrc + (size_t)col[e] * DIM))[lane];
        if (APPLY_BN) w = relu2(w * sc + sh);
        acc.x += (float)w[0]; acc.y += (float)w[1];
    }
    f16x2 o;
    o[0] = (_Float16)acc.x; o[1] = (_Float16)acc.y;
    ((f16x2*)(agg + (size_t)node * DIM))[lane] = o;
}

// ---------------- MFMA GEMM, register-held B, no LDS, packed-f16 prologue -------------
// Block = 4 waves, 32 rows. Wave w owns cols [w*NC/4, (w+1)*NC/4).
// MODE 0: A[m][k] = (1+eps) * f(A0[m][k]) + A1[m][k], f = relu(x*sc+sh) if APPLY_BN
// MODE 1: A[m][k] = relu(A0[m][k]*sc[k] + sh[k])
// Bt f16 [NC][K], L2-broadcast. Stats: osum/osq += column sums/sumsq of C.
template <int K, int NC, int MODE, int APPLY_BN, int STATS>
__global__ __launch_bounds__(256) void gemm_mfma(
    const _Float16* __restrict__ A0h, const _Float16* __restrict__ A1h,
    const _Float16* __restrict__ Bt, const float* __restrict__ bias,
    const _Float16* __restrict__ scale16, const _Float16* __restrict__ shift16,
    const float* __restrict__ epsArr, int layer, _Float16* __restrict__ Cout,
    float* __restrict__ osum, float* __restrict__ osq) {
    const int WC = NC / 4;        // cols per wave (64 or 32)
    const int NT = WC / 16;       // 16-col tiles per wave (4 or 2)
    const int KI = K / 32;        // k-steps (4 or 8)
    int tid = threadIdx.x;
    int wave = tid >> 6, lane = tid & 63, quad = lane >> 4, l16 = lane & 15;
    int n0 = wave * WC;

    // B fragments in registers, loaded once (same data across blocks -> L2 hits)
    f16x8 bfrag[NT][KI];
    #pragma unroll
    for (int nt = 0; nt < NT; ++nt)
        #pragma unroll
        for (int kt = 0; kt < KI; ++kt)
            bfrag[nt][kt] = *(const f16x8*)(Bt + (size_t)(n0 + nt * 16 + l16) * K + kt * 32 + quad * 8);

    int m0 = blockIdx.x * 32;
    int mt1 = m0 + 16;
    bool t1v = (mt1 < N_NODES);        // 50000 % 16 == 0: tiles fully valid or fully invalid
    int mrow0 = m0 + l16;
    int mrow1 = t1v ? (mt1 + l16) : mrow0;

    f32x4 acc0[NT], acc1[NT];
    #pragma unroll
    for (int nt = 0; nt < NT; ++nt) { acc0[nt] = (f32x4){0,0,0,0}; acc1[nt] = (f32x4){0,0,0,0}; }

    f16x8 evv;
    {
        _Float16 ev = (MODE == 0) ? (_Float16)(1.0f + epsArr[layer]) : (_Float16)0;
        #pragma unroll
        for (int j = 0; j < 8; ++j) evv[j] = ev;
    }

    #pragma unroll
    for (int kt = 0; kt < KI; ++kt) {
        int kb = kt * 32 + quad * 8;
        f16x8 scv, shv;
        if (MODE == 1 || APPLY_BN) {
            scv = *(const f16x8*)(scale16 + kb);
            shv = *(const f16x8*)(shift16 + kb);
        }
        f16x8 afrag0, afrag1;
        if (MODE == 0) {
            f16x8 h0 = *(const f16x8*)(A0h + (size_t)mrow0 * K + kb);
            f16x8 h1 = *(const f16x8*)(A0h + (size_t)mrow1 * K + kb);
            f16x8 a0 = *(const f16x8*)(A1h + (size_t)mrow0 * K + kb);
            f16x8 a1 = *(const f16x8*)(A1h + (size_t)mrow1 * K + kb);
            if (APPLY_BN) {
                h0 = relu8(h0 * scv + shv);
                h1 = relu8(h1 * scv + shv);
            }
            afrag0 = evv * h0 + a0;
            afrag1 = evv * h1 + a1;
        } else {
            f16x8 z0 = *(const f16x8*)(A0h + (size_t)mrow0 * K + kb);
            f16x8 z1 = *(const f16x8*)(A0h + (size_t)mrow1 * K + kb);
            afrag0 = relu8(z0 * scv + shv);
            afrag1 = relu8(z1 * scv + shv);
        }
        #pragma unroll
        for (int nt = 0; nt < NT; ++nt) {
            acc0[nt] = __builtin_amdgcn_mfma_f32_16x16x32_f16(afrag0, bfrag[nt][kt], acc0[nt], 0, 0, 0);
            acc1[nt] = __builtin_amdgcn_mfma_f32_16x16x32_f16(afrag1, bfrag[nt][kt], acc1[nt], 0, 0, 0);
        }
    }

    // epilogue: C layout col = l16, row = quad*4 + r
    #pragma unroll
    for (int nt = 0; nt < NT; ++nt) {
        int c = n0 + nt * 16 + l16;
        float bv = bias[c];
        float v0[4], v1[4];
        #pragma unroll
        for (int r = 0; r < 4; ++r) { v0[r] = acc0[nt][r] + bv; v1[r] = acc1[nt][r] + bv; }
        #pragma unroll
        for (int r = 0; r < 4; ++r)
            Cout[(size_t)(m0 + quad * 4 + r) * NC + c] = (_Float16)v0[r];
        if (t1v) {
            #pragma unroll
            for (int r = 0; r < 4; ++r)
                Cout[(size_t)(mt1 + quad * 4 + r) * NC + c] = (_Float16)v1[r];
        }
        if (STATS) {
            float s = v0[0] + v0[1] + v0[2] + v0[3];
            float q = v0[0]*v0[0] + v0[1]*v0[1] + v0[2]*v0[2] + v0[3]*v0[3];
            if (t1v) {
                s += v1[0] + v1[1] + v1[2] + v1[3];
                q += v1[0]*v1[0] + v1[1]*v1[1] + v1[2]*v1[2] + v1[3]*v1[3];
            }
            s += __shfl_xor(s, 16, 64); s += __shfl_xor(s, 32, 64);
            q += __shfl_xor(q, 16, 64); q += __shfl_xor(q, 32, 64);
            if (lane < 16) {
                atomicAdd(&osum[c], s);
                atomicAdd(&osq[c], q);
            }
        }
    }
}

// finalize BN -> f16 scale/shift arrays for packed-f16 consumers
template <int C>
__global__ void bn_finalize(const float* __restrict__ ssum, const float* __restrict__ ssq,
                            const float* __restrict__ g, const float* __restrict__ b,
                            _Float16* __restrict__ scale16, _Float16* __restrict__ shift16) {
    int c = threadIdx.x;
    float mean = ssum[c] * (1.0f / N_NODES);
    float var = ssq[c] * (1.0f / N_NODES) - mean * mean;
    float sc = g[c] * rsqrtf(var + 1e-5f);
    scale16[c] = (_Float16)sc;
    shift16[c] = (_Float16)(b[c] - mean * sc);
}

// ---------------- pooling ----------------
__global__ void count_graph(const int* __restrict__ batch, int* __restrict__ gcnt) {
    int n = blockIdx.x * 256 + threadIdx.x;
    if (n < N_NODES) atomicAdd(&gcnt[batch[n]], 1);
}

__global__ void scan_g(const int* __restrict__ gcnt, int* __restrict__ gptr) {
    __shared__ int s[512];
    int v = gcnt[threadIdx.x];
    s[threadIdx.x] = v;
    __syncthreads();
    for (int off = 1; off < 512; off <<= 1) {
        int t = (threadIdx.x >= off) ? s[threadIdx.x - off] : 0;
        __syncthreads();
        s[threadIdx.x] += t;
        __syncthreads();
    }
    gptr[threadIdx.x] = s[threadIdx.x] - v;
    if (threadIdx.x == 511) gptr[512] = s[511];
}

__global__ void pool16(const _Float16* __restrict__ h, const int* __restrict__ gptr,
                       float* __restrict__ hg) {
    __shared__ float red[4][128];
    int g = blockIdx.x;
    int wave = threadIdx.x >> 6, lane = threadIdx.x & 63;
    int n0 = gptr[g], n1 = gptr[g + 1];
    float2 acc = {0.f, 0.f};
    for (int n = n0 + wave; n < n1; n += 4) {
        f16x2 v = ((const f16x2*)(h + (size_t)n * DIM))[lane];
        acc.x += (float)v[0]; acc.y += (float)v[1];
    }
    red[wave][lane * 2] = acc.x;
    red[wave][lane * 2 + 1] = acc.y;
    __syncthreads();
    if (wave == 0) {
        float tx = red[0][lane*2]   + red[1][lane*2]   + red[2][lane*2]   + red[3][lane*2];
        float ty = red[0][lane*2+1] + red[1][lane*2+1] + red[2][lane*2+1] + red[3][lane*2+1];
        float inv = 1.0f / fmaxf((float)(n1 - n0), 1.0f);
        float2 r; r.x = tx * inv; r.y = ty * inv;
        ((float2*)(hg + (size_t)g * DIM))[lane] = r;
    }
}

__global__ void outk(const float* __restrict__ hg, const float* __restrict__ Wout,
                     const float* __restrict__ bout, float* __restrict__ out) {
    __shared__ float s[DIM];
    int g = blockIdx.x;
    for (int d = threadIdx.x; d < DIM; d += 64) s[d] = hg[(size_t)g * DIM + d];
    __syncthreads();
    int t = threadIdx.x;
    if (t < TDIM) {
        float acc = bout[t];
        for (int d = 0; d < DIM; ++d) acc += s[d] * Wout[d * TDIM + t];
        out[g * TDIM + t] = acc;
    }
}

extern "C" void kernel_launch(void* const* d_in, const int* in_sizes, int n_in,
                              void* d_out, int out_size, void* d_ws, size_t ws_size,
                              hipStream_t stream) {
    const int*   x     = (const int*)d_in[0];
    const int*   ei    = (const int*)d_in[1];
    const int*   batch = (const int*)d_in[2];
    const float* emb   = (const float*)d_in[3];
    const float* W1    = (const float*)d_in[4];
    const float* b1    = (const float*)d_in[5];
    const float* g1    = (const float*)d_in[6];
    const float* be1   = (const float*)d_in[7];
    const float* W2    = (const float*)d_in[8];
    const float* b2    = (const float*)d_in[9];
    const float* epsA  = (const float*)d_in[10];
    const float* bng   = (const float*)d_in[11];
    const float* bnb   = (const float*)d_in[12];
    const float* Wout  = (const float*)d_in[13];
    const float* bout  = (const float*)d_in[14];
    float* out = (float*)d_out;

    const int* srcIdx = ei;
    const int* dstIdx = ei + N_EDGES;

    char* base = (char*)d_ws;
    size_t off = 0;
    auto alloc = [&](size_t bytes) {
        char* p = base + off;
        off = (off + bytes + 255) & ~(size_t)255;
        return p;
    };
    _Float16* hraw  = (_Float16*)alloc((size_t)N_NODES * DIM * 2);
    _Float16* hrel  = (_Float16*)alloc((size_t)N_NODES * DIM * 2);   // layer-0 gather input
    _Float16* agg   = (_Float16*)alloc((size_t)N_NODES * DIM * 2);
    _Float16* z16   = (_Float16*)alloc((size_t)N_NODES * DIM2 * 2);
    _Float16* h2    = (_Float16*)alloc((size_t)N_NODES * DIM * 2);
    _Float16* W1t   = (_Float16*)alloc((size_t)NLAYER * DIM * DIM2 * 2);
    _Float16* W2t   = (_Float16*)alloc((size_t)NLAYER * DIM * DIM2 * 2);
    int*   rp    = (int*)alloc((N_NODES + 1) * 4);
    int*   tmpN  = (int*)alloc(N_NODES * 4);
    int*   col   = (int*)alloc(N_EDGES * 4);
    int*   bsum  = (int*)alloc(128 * 4);
    int*   boff  = (int*)alloc(128 * 4);
    int*   gcnt  = (int*)alloc(NGRAPH * 4);
    int*   gptr  = (int*)alloc((NGRAPH + 1) * 4);
    float* stats = (float*)alloc(768 * 4);     // [ssum1:256][ssq1:256][ssum2:128][ssq2:128]
    _Float16* scl1h = (_Float16*)alloc(DIM2 * 2);
    _Float16* sft1h = (_Float16*)alloc(DIM2 * 2);
    _Float16* scl2h = (_Float16*)alloc(DIM * 2);
    _Float16* sft2h = (_Float16*)alloc(DIM * 2);
    float* hg    = (float*)alloc((size_t)NGRAPH * DIM * 4);

    float* ssum1 = stats, *ssq1 = stats + 256, *ssum2 = stats + 512, *ssq2 = stats + 640;

    convert_w<<<(NLAYER * DIM * DIM2 + 255) / 256, 256, 0, stream>>>(W1, W2, W1t, W2t);
    atom_encoder<<<N_NODES / 4, 256, 0, stream>>>(x, emb, hraw, hrel);

    // CSR build (reused by all 5 layers)
    hipMemsetAsync(tmpN, 0, N_NODES * 4, stream);
    count_deg<<<(N_EDGES + 255) / 256, 256, 0, stream>>>(dstIdx, tmpN);
    scan_a<<<98, 512, 0, stream>>>(tmpN, rp, bsum);
    scan_b<<<1, 128, 0, stream>>>(bsum, boff);
    scan_c<<<98, 512, 0, stream>>>(rp, boff);
    hipMemsetAsync(tmpN, 0, N_NODES * 4, stream);
    fill_csr<<<(N_EDGES + 255) / 256, 256, 0, stream>>>(srcIdx, dstIdx, rp, tmpN, col);

    // graph pooling CSR
    hipMemsetAsync(gcnt, 0, NGRAPH * 4, stream);
    count_graph<<<(N_NODES + 255) / 256, 256, 0, stream>>>(batch, gcnt);
    scan_g<<<1, 512, 0, stream>>>(gcnt, gptr);

    const int GG = (N_NODES + 31) / 32;   // 1563 blocks

    for (int i = 0; i < NLAYER; ++i) {
        if (i == 0)
            gather_agg<0><<<N_NODES / 4, 256, 0, stream>>>(hrel, rp, col, nullptr, nullptr, agg);
        else
            gather_agg<1><<<N_NODES / 4, 256, 0, stream>>>(h2, rp, col, scl2h, sft2h, agg);

        hipMemsetAsync(stats, 0, 768 * 4, stream);

        if (i == 0)
            gemm_mfma<128, 256, 0, 0, 1><<<GG, 256, 0, stream>>>(
                hraw, agg, W1t, b1, nullptr, nullptr, epsA, 0, z16, ssum1, ssq1);
        else
            gemm_mfma<128, 256, 0, 1, 1><<<GG, 256, 0, stream>>>(
                h2, agg, W1t + (size_t)i * DIM * DIM2, b1 + i * 256,
                scl2h, sft2h, epsA, i, z16, ssum1, ssq1);

        bn_finalize<256><<<1, 256, 0, stream>>>(ssum1, ssq1, g1 + i * 256, be1 + i * 256, scl1h, sft1h);

        if (i < NLAYER - 1) {
            gemm_mfma<256, 128, 1, 0, 1><<<GG, 256, 0, stream>>>(
                z16, nullptr, W2t + (size_t)i * DIM * DIM2, b2 + i * 128,
                scl1h, sft1h, epsA, i, h2, ssum2, ssq2);
            bn_finalize<128><<<1, 128, 0, stream>>>(ssum2, ssq2, bng + i * 128, bnb + i * 128, scl2h, sft2h);
        } else {
            gemm_mfma<256, 128, 1, 0, 0><<<GG, 256, 0, stream>>>(
                z16, nullptr, W2t + (size_t)i * DIM * DIM2, b2 + i * 128,
                scl1h, sft1h, epsA, i, h2, ssum2, ssq2);
        }
    }

    pool16<<<NGRAPH, 256, 0, stream>>>(h2, gptr, hg);
    outk<<<NGRAPH, 64, 0, stream>>>(hg, Wout, bout, out);
}